// Round 23
// baseline (492.117 us; speedup 1.0000x reference)
//
#include <hip/hip_runtime.h>
#include <cmath>

namespace {
constexpr int B_ = 16, T_ = 192, N_ = 24, D_ = 128, M_ = 9, H_ = 8, F_ = 16, FF_ = 256;
constexpr int ND_ = N_ * D_;                       // 3072
constexpr int ROWS_ = T_ * B_;                     // 3072
constexpr long long SZ_ = (long long)ROWS_ * ND_;  // 9437184 elements
constexpr long long WL_ = 2064384;                 // ushorts per layer weight area
}

typedef __attribute__((ext_vector_type(8))) short bf16x8_t;
typedef __attribute__((ext_vector_type(4))) short bf16x4_t;
typedef __attribute__((ext_vector_type(4))) float f32x4_t;

static __device__ __forceinline__ ushort f2bf(float f) {
  union { float f; uint u; } v; v.f = f;
  uint r = v.u + 0x7fffu + ((v.u >> 16) & 1u);   // RNE
  return (ushort)(r >> 16);
}
static __device__ __forceinline__ float bf2f(ushort u) {
  union { uint u; float f; } v; v.u = ((uint)u) << 16; return v.f;
}
static __device__ __forceinline__ uint cvtpk(float lo, float hi) {
  uint r;
  asm("v_cvt_pk_bf16_f32 %0, %1, %2" : "=v"(r) : "v"(lo), "v"(hi));
  return r;
}
// fragment-major index for canonical W[e][k], tile 128 x (KQ*32)
static __device__ __forceinline__ int fragIdx(int e, int k, int KQ) {
  int n = e >> 4, lr = e & 15;
  int kq = k >> 5, krem = k & 31;
  int hi = krem >> 4, rem = krem & 15;
  int lg = rem >> 2, jj = rem & 3;
  return (((n * KQ + kq) * 64 + lg * 16 + lr) << 3) + hi * 4 + jj;
}

// ---------------- positional-encoding table: pe[t][c], 192x3072 ----------------
__global__ __launch_bounds__(256) void k_pe(float* __restrict__ pe)
{
  int i = blockIdx.x * 256 + threadIdx.x;
  if (i >= T_ * ND_) return;
  int t = i / ND_, c = i % ND_;
  float freq = expf((float)(2 * (c >> 1)) * (-9.210340371976184f / 3072.0f));
  float ang = (float)t * freq;
  pe[i] = (c & 1) ? cosf(ang) : sinf(ang);
}

// ---------------- embedding + PE -> bf16 X ----------------
__global__ __launch_bounds__(256) void k_embed(const float* __restrict__ in,
                                               const float* __restrict__ Wemb,
                                               const float* __restrict__ bemb,
                                               const float* __restrict__ pe,
                                               ushort* __restrict__ Xb)
{
  int row = blockIdx.x;            // t*B + b
  int t = row / B_, b = row % B_;
  int tid = threadIdx.x;
  __shared__ float inr[N_ * M_];
  const float* ip = in + ((size_t)b * T_ + t) * (N_ * M_);
  if (tid < N_ * M_) inr[tid] = ip[tid];
  __syncthreads();
  uint* Xr = (uint*)(Xb + (size_t)row * ND_);
  const float* per = pe + (size_t)t * ND_;
  for (int cc = tid; cc < ND_ / 2; cc += 256) {
    int c = cc * 2;
    int n = c >> 7;
    int d = c & 127;
    const float* xr = &inr[n * M_];
    float a0 = bemb[n * D_ + d] + per[c];
    float a1 = bemb[n * D_ + d + 1] + per[c + 1];
    const float* wp = Wemb + (size_t)(n * M_) * D_ + d;
    #pragma unroll
    for (int m = 0; m < M_; ++m) {
      float xm = xr[m];
      a0 += xm * wp[(size_t)m * D_];
      a1 += xm * wp[(size_t)m * D_ + 1];
    }
    Xr[cc] = (uint)f2bf(a0) | ((uint)f2bf(a1) << 16);
  }
}

// ---------------- spatial weight/bias packing, FRAGMENT layout ----------------
__global__ __launch_bounds__(256) void k_pack_sp(const float* __restrict__ saWq,
                                                 const float* __restrict__ sabq,
                                                 const float* __restrict__ saWk,
                                                 const float* __restrict__ sabk,
                                                 const float* __restrict__ saWv,
                                                 const float* __restrict__ sabv,
                                                 ushort* __restrict__ wts,
                                                 float* __restrict__ fb)
{
  int l = blockIdx.y;
  int i = blockIdx.x * 256 + threadIdx.x;
  ushort* wl = wts + (long long)l * WL_;
  float* fl = fb + l * 3328;
  if (i < 393216) {                       // sWq frag: per joint gz, tile 128x128
    int gz = i >> 14, il = i & 16383;
    int j = il & 7;
    int lane = (il >> 3) & 63;
    int nk = il >> 9;                     // n*4+kq
    int kq = nk & 3, n8 = nk >> 2;
    int lr = lane & 15, lg = lane >> 4;
    int e = n8 * 16 + lr;
    int d = kq * 32 + lg * 4 + (j & 3) + ((j >> 2) << 4);
    int h = e >> 4, f = e & 15;
    wl[i] = f2bf(saWq[(long long)l * 393216 + (((size_t)h * N_ + gz) * D_ + d) * F_ + f]);
  } else if (i < 409600) {                // sWk frag: tile 128x128
    int il = i - 393216;
    int j = il & 7;
    int lane = (il >> 3) & 63;
    int nk = il >> 9;
    int kq = nk & 3, n8 = nk >> 2;
    int lr = lane & 15, lg = lane >> 4;
    int e = n8 * 16 + lr;
    int d = kq * 32 + lg * 4 + (j & 3) + ((j >> 2) << 4);
    int h = e >> 4, f = e & 15;
    wl[i] = f2bf(saWk[(long long)l * 16384 + ((size_t)h * D_ + d) * F_ + f]);
  } else if (i < 425984) {                // sWv frag
    int il = i - 409600;
    int j = il & 7;
    int lane = (il >> 3) & 63;
    int nk = il >> 9;
    int kq = nk & 3, n8 = nk >> 2;
    int lr = lane & 15, lg = lane >> 4;
    int e = n8 * 16 + lr;
    int d = kq * 32 + lg * 4 + (j & 3) + ((j >> 2) << 4);
    int h = e >> 4, f = e & 15;
    wl[i] = f2bf(saWv[(long long)l * 16384 + ((size_t)h * D_ + d) * F_ + f]);
  } else if (i < 429056) {                // bqP[n][e]
    int j = i - 425984;
    int n = j >> 7, e = j & 127, h = e >> 4, f = e & 15;
    fl[j] = sabq[l * 3072 + ((size_t)h * N_ + n) * F_ + f];
  } else if (i < 429184) {
    int j = i - 429056, h = j >> 4, f = j & 15;
    fl[3072 + j] = sabk[l * 128 + h * F_ + f];
  } else if (i < 429312) {
    int j = i - 429184, h = j >> 4, f = j & 15;
    fl[3200 + j] = sabv[l * 128 + h * F_ + f];
  }
}

// ---------------- transposed weight packing -> FRAGMENT layout -------------------
struct PackWArgs {
  const float* src[6];     // layer-0 bases: taWq, taWk, taWv, taWo, ffW1, ffW2
  ushort* wts;
};
__global__ __launch_bounds__(256) void k_pack_w(PackWArgs args)
{
  __shared__ float tile[64][65];
  int l = blockIdx.y;
  int x = blockIdx.x;
  ushort* wl = args.wts + (long long)l * WL_;
  const float* sp; ushort* dp;
  int bx, by, Rr, Cc, mode;
  if (x < 384) {
    int ten = x / 96, rem = x % 96, g = rem / 4, tl = rem % 4;
    bx = tl & 1; by = tl >> 1; Rr = 128; Cc = 128; mode = 0;
    sp = args.src[ten] + (long long)l * 393216 + (long long)g * 16384;
    dp = wl + 425984 + (long long)ten * 393216 + (long long)g * 16384;
  } else if (x < 392) {
    int idx = x - 384; bx = idx & 3; by = idx >> 2; Rr = 128; Cc = 256; mode = 1;
    sp = args.src[4] + (long long)l * 32768;
    dp = wl + 1998848;
  } else {
    int idx = x - 392; bx = idx & 1; by = idx >> 1; Rr = 256; Cc = 128; mode = 2;
    sp = args.src[5] + (long long)l * 32768;
    dp = wl + 2031616;
  }
  int c0 = bx * 64, r0 = by * 64;
  int ci = threadIdx.x & 63, rq = threadIdx.x >> 6;
  #pragma unroll
  for (int k = 0; k < 16; ++k) {
    int r = rq * 16 + k;
    tile[r][ci] = sp[(long long)(r0 + r) * Cc + c0 + ci];
  }
  __syncthreads();
  int ri = threadIdx.x & 63, cq = threadIdx.x >> 6;
  #pragma unroll
  for (int k = 0; k < 16; ++k) {
    int c = cq * 16 + k;
    int eg = c0 + c;          // output-col (e) dim
    int kg = r0 + ri;         // k dim
    int idx;
    if (mode == 1)      idx = (eg >> 7) * 16384 + fragIdx(eg & 127, kg, 4);
    else if (mode == 2) idx = fragIdx(eg, kg, 8);
    else                idx = fragIdx(eg, kg, 4);
    dp[idx] = f2bf(tile[ri][c]);
  }
}

// ---------------- unified 6-projection MFMA GEMM (2 row-tiles/block) ------------
struct Qkv6Args {
  const ushort* W[6];
  const float* bias[6];
  ushort* C[6];
  long long wGroup[6];
  int biasGroup[6];
  int tpose[6];
};
__global__ __launch_bounds__(256) void k_qkv6(const ushort* __restrict__ A, Qkv6Args args)
{
  __shared__ ushort Wl[16384];          // 32 KB, flat fragment layout
  int p = blockIdx.y;
  int gz = blockIdx.z;
  int tid = threadIdx.x;
  int lane = tid & 63, wid = tid >> 6;
  int lr = lane & 15, lg = lane >> 4;
  {
    const ushort* Wf = args.W[p] + (long long)gz * args.wGroup[p];
    #pragma unroll
    for (int it = 0; it < 8; ++it) {
      int idx = (it * 256 + tid) << 3;
      *(uint4*)&Wl[idx] = *(const uint4*)(Wf + idx);
    }
  }
  __syncthreads();
  const float* bb = args.bias[p] + (long long)gz * args.biasGroup[p];
  #pragma unroll
  for (int tt = 0; tt < 2; ++tt) {
    int row0 = (blockIdx.x * 2 + tt) * 64 + wid * 16;
    union { bf16x8_t v; bf16x4_t h[2]; } au[4];
    {
      const ushort* ap = A + (long long)gz * 128 + (long long)(row0 + lr) * ND_ + lg * 4;
      #pragma unroll
      for (int kq = 0; kq < 4; ++kq) {
        au[kq].h[0] = *(const bf16x4_t*)(ap + kq * 32);
        au[kq].h[1] = *(const bf16x4_t*)(ap + kq * 32 + 16);
      }
    }
    f32x4_t acc[8];
    #pragma unroll
    for (int n = 0; n < 8; ++n) acc[n] = (f32x4_t){0.f, 0.f, 0.f, 0.f};
    #pragma unroll
    for (int n = 0; n < 8; ++n) {
      #pragma unroll
      for (int kq = 0; kq < 4; ++kq) {
        bf16x8_t bu = *(const bf16x8_t*)&Wl[((n * 4 + kq) * 64 + lane) << 3];
        acc[n] = __builtin_amdgcn_mfma_f32_16x16x32_bf16(au[kq].v, bu, acc[n], 0, 0, 0);
      }
    }
    if (args.tpose[p]) {
      ushort* Cp = args.C[p];
      #pragma unroll
      for (int n = 0; n < 8; ++n) {
        float bv = bb[n * 16 + lr];
        #pragma unroll
        for (int r = 0; r < 4; ++r) {
          int rg = row0 + lg * 4 + r;
          int ttg = rg >> 4, bI = rg & 15;
          long long gI = ((long long)bI * N_ + gz) * H_ + n;
          Cp[(gI * T_ + ttg) * F_ + lr] = f2bf(acc[n][r] + bv);
        }
      }
    } else {
      ushort* Cp = args.C[p] + (long long)gz * 128;
      #pragma unroll
      for (int n = 0; n < 8; ++n) {
        float bv = bb[n * 16 + lr];
        #pragma unroll
        for (int r = 0; r < 4; ++r)
          Cp[(long long)(row0 + lg * 4 + r) * ND_ + n * 16 + lr] = f2bf(acc[n][r] + bv);
      }
    }
  }
}

// ---------------- FF1 (flat-LDS frag staging, 2 row-tiles/block) ----------------
__global__ __launch_bounds__(256) void k_ff1(
    const ushort* __restrict__ A, const ushort* __restrict__ Wt,
    const float* __restrict__ bias, ushort* __restrict__ Cout)
{
  __shared__ ushort Wl[16384];
  int tid = threadIdx.x;
  int lane = tid & 63, wid = tid >> 6;
  int lr = lane & 15, lg = lane >> 4;
  {
    const ushort* Wf = Wt + (long long)blockIdx.y * 16384;
    #pragma unroll
    for (int it = 0; it < 8; ++it) {
      int idx = (it * 256 + tid) << 3;
      *(uint4*)&Wl[idx] = *(const uint4*)(Wf + idx);
    }
  }
  __syncthreads();
  const float* bb = bias + blockIdx.y * 128;
  int ccolBase = blockIdx.y * 128 + lr;
  #pragma unroll
  for (int tt = 0; tt < 2; ++tt) {
    int row0 = (blockIdx.x * 2 + tt) * 64 + wid * 16;
    union { bf16x8_t v; bf16x4_t h[2]; } au[4];
    {
      const ushort* ap = A + (long long)(row0 + lr) * 128 + lg * 4;
      #pragma unroll
      for (int kq = 0; kq < 4; ++kq) {
        au[kq].h[0] = *(const bf16x4_t*)(ap + kq * 32);
        au[kq].h[1] = *(const bf16x4_t*)(ap + kq * 32 + 16);
      }
    }
    f32x4_t acc[8];
    #pragma unroll
    for (int n = 0; n < 8; ++n) acc[n] = (f32x4_t){0.f, 0.f, 0.f, 0.f};
    #pragma unroll
    for (int n = 0; n < 8; ++n) {
      #pragma unroll
      for (int kq = 0; kq < 4; ++kq) {
        bf16x8_t bu = *(const bf16x8_t*)&Wl[((n * 4 + kq) * 64 + lane) << 3];
        acc[n] = __builtin_amdgcn_mfma_f32_16x16x32_bf16(au[kq].v, bu, acc[n], 0, 0, 0);
      }
    }
    #pragma unroll
    for (int n = 0; n < 8; ++n) {
      float bv = bb[n * 16 + lr];
      #pragma unroll
      for (int r = 0; r < 4; ++r) {
        float v = fmaxf(acc[n][r] + bv, 0.f);
        Cout[(long long)(row0 + lg * 4 + r) * 256 + ccolBase + n * 16] = f2bf(v);
      }
    }
  }
}

// ---------------- FF2 + residual + per-joint LN_128, 2 row-tiles/block -----------
__global__ __launch_bounds__(256) void k_ff2_ln(
    const ushort* __restrict__ A,      // hB: 73728 x 256
    const ushort* __restrict__ Wt,     // W2 frag layout (KQ=8)
    const float* __restrict__ bias,    // ff_b2 (128)
    const ushort* __restrict__ Res,    // Ab flat 73728 x 128
    const float* __restrict__ g,       // lns_g (128)
    const float* __restrict__ be,      // lns_b (128)
    ushort* __restrict__ Xb)           // flat 73728 x 128
{
  __shared__ ushort Wl[32768];          // 64 KB, flat fragment layout
  int tid = threadIdx.x;
  int lane = tid & 63, wid = tid >> 6;
  int lr = lane & 15, lg = lane >> 4;
  {
    #pragma unroll
    for (int it = 0; it < 16; ++it) {
      int idx = (it * 256 + tid) << 3;
      *(uint4*)&Wl[idx] = *(const uint4*)(Wt + idx);
    }
  }
  __syncthreads();
  #pragma unroll
  for (int tt = 0; tt < 2; ++tt) {
    int row0 = (blockIdx.x * 2 + tt) * 64 + wid * 16;
    union { bf16x8_t v; bf16x4_t h[2]; } au[8];
    {
      const ushort* ap = A + (long long)(row0 + lr) * 256 + lg * 4;
      #pragma unroll
      for (int kq = 0; kq < 8; ++kq) {
        au[kq].h[0] = *(const bf16x4_t*)(ap + kq * 32);
        au[kq].h[1] = *(const bf16x4_t*)(ap + kq * 32 + 16);
      }
    }
    f32x4_t acc[8];
    #pragma unroll
    for (int n = 0; n < 8; ++n) acc[n] = (f32x4_t){0.f, 0.f, 0.f, 0.f};
    #pragma unroll
    for (int n = 0; n < 8; ++n) {
      #pragma unroll
      for (int kq = 0; kq < 8; ++kq) {
        bf16x8_t bu = *(const bf16x8_t*)&Wl[((n * 8 + kq) * 64 + lane) << 3];
        acc[n] = __builtin_amdgcn_mfma_f32_16x16x32_bf16(au[kq].v, bu, acc[n], 0, 0, 0);
      }
    }
    // epilogue: + bias + residual, per-row LN over 128
    float s[4] = {0.f, 0.f, 0.f, 0.f};
    float s2[4] = {0.f, 0.f, 0.f, 0.f};
    #pragma unroll
    for (int n = 0; n < 8; ++n) {
      float bv = bias[n * 16 + lr];
      #pragma unroll
      for (int r = 0; r < 4; ++r) {
        float v = acc[n][r] + bv
                + bf2f(Res[(long long)(row0 + lg * 4 + r) * 128 + n * 16 + lr]);
        acc[n][r] = v;
        s[r] += v;
        s2[r] += v * v;
      }
    }
    #pragma unroll
    for (int m = 1; m < 16; m <<= 1) {
      #pragma unroll
      for (int r = 0; r < 4; ++r) {
        s[r] += __shfl_xor(s[r], m, 64);
        s2[r] += __shfl_xor(s2[r], m, 64);
      }
    }
    #pragma unroll
    for (int r = 0; r < 4; ++r) {
      float mu = s[r] * (1.f / 128.f);
      float var = s2[r] * (1.f / 128.f) - mu * mu;
      float rs = rsqrtf(var + 1e-5f);
      long long rb = (long long)(row0 + lg * 4 + r) * 128;
      #pragma unroll
      for (int n = 0; n < 8; ++n) {
        int col = n * 16 + lr;
        Xb[rb + col] = f2bf((acc[n][r] - mu) * rs * g[col] + be[col]);
      }
    }
  }
}

// ---------------- oproj (2 row-tiles/block); A transposed TT layout --------------
__global__ __launch_bounds__(256) void k_oproj(const ushort* __restrict__ A,
                                               const ushort* __restrict__ Wt,
                                               const float* __restrict__ bias,
                                               ushort* __restrict__ Cout)
{
  __shared__ ushort Wl[16384];
  int gz = blockIdx.z;
  int tid = threadIdx.x;
  int lane = tid & 63, wid = tid >> 6;
  int lr = lane & 15, lg = lane >> 4;
  {
    const ushort* Wf = Wt + (long long)gz * 16384;
    #pragma unroll
    for (int it = 0; it < 8; ++it) {
      int idx = (it * 256 + tid) << 3;
      *(uint4*)&Wl[idx] = *(const uint4*)(Wf + idx);
    }
  }
  __syncthreads();
  const float* bb = bias + (long long)gz * 128;
  ushort* C = Cout + (long long)gz * 128;
  #pragma unroll
  for (int tt = 0; tt < 2; ++tt) {
    int row0 = (blockIdx.x * 2 + tt) * 64 + wid * 16;   // mult of 16: t uniform, b = lr
    int tW = row0 >> 4;
    union { bf16x8_t v; bf16x4_t h[2]; } au[4];
    {
      const ushort* ab = A + (((long long)lr * N_ + gz) * H_) * ((long long)T_ * F_)
                           + (long long)tW * F_ + lg * 4;
      #pragma unroll
      for (int kq = 0; kq < 4; ++kq) {
        au[kq].h[0] = *(const bf16x4_t*)(ab + (long long)(2 * kq) * (T_ * F_));
        au[kq].h[1] = *(const bf16x4_t*)(ab + (long long)(2 * kq + 1) * (T_ * F_));
      }
    }
    f32x4_t acc[8];
    #pragma unroll
    for (int n = 0; n < 8; ++n) acc[n] = (f32x4_t){0.f, 0.f, 0.f, 0.f};
    #pragma unroll
    for (int n = 0; n < 8; ++n) {
      #pragma unroll
      for (int kq = 0; kq < 4; ++kq) {
        bf16x8_t bu = *(const bf16x8_t*)&Wl[((n * 4 + kq) * 64 + lane) << 3];
        acc[n] = __builtin_amdgcn_mfma_f32_16x16x32_bf16(au[kq].v, bu, acc[n], 0, 0, 0);
      }
    }
    #pragma unroll
    for (int n = 0; n < 8; ++n) {
      float bv = bb[n * 16 + lr];
      #pragma unroll
      for (int r = 0; r < 4; ++r)
        C[(long long)(row0 + lg * 4 + r) * ND_ + n * 16 + lr] = f2bf(acc[n][r] + bv);
    }
  }
}

// ---------------- fused spatial attention + LN -> T2b, register-resident O --------
__global__ __launch_bounds__(256) void k_spatial_ln(const ushort* __restrict__ Qg,
                                                    const ushort* __restrict__ Kg,
                                                    const ushort* __restrict__ Vg,
                                                    const ushort* __restrict__ Xb,
                                                    const float* __restrict__ g,
                                                    const float* __restrict__ be,
                                                    ushort* __restrict__ T2b)
{
  int row = blockIdx.x;
  int tid = threadIdx.x;
  __shared__ float Ks[8 * 409];
  __shared__ float Vs[8 * 409];
  __shared__ float ps[4], ps2[4];
  {
    const uint4* K4 = (const uint4*)(Kg + (size_t)row * ND_);
    const uint4* V4 = (const uint4*)(Vg + (size_t)row * ND_);
    for (int i8 = tid; i8 < 384; i8 += 256) {
      int n = i8 >> 4, e8 = (i8 & 15) * 8;
      int h = e8 >> 4, f0 = e8 & 15;
      int basei = h * 409 + n * 17 + f0;
      union { uint4 u; ushort s[8]; } kv, vv;
      kv.u = K4[i8];
      vv.u = V4[i8];
      #pragma unroll
      for (int j = 0; j < 8; ++j) {
        Ks[basei + j] = bf2f(kv.s[j]);
        Vs[basei + j] = bf2f(vv.s[j]);
      }
    }
  }
  __syncthreads();
  float o[F_];
  float s = 0.f, s2 = 0.f;
  int n = tid >> 3, h = tid & 7;
  int cbase = n * D_ + h * F_;
  if (tid < 192) {
    float q[F_];
    {
      const ushort* qp = Qg + (size_t)row * ND_ + cbase;
      union { uint4 u[2]; ushort s[16]; } qv;
      qv.u[0] = *(const uint4*)qp;
      qv.u[1] = *(const uint4*)(qp + 8);
      #pragma unroll
      for (int f = 0; f < F_; ++f) q[f] = bf2f(qv.s[f]);
    }
    float sc[N_];
    float mx = -1e30f;
    const float* Kh = &Ks[h * 409];
    for (int m = 0; m < N_; ++m) {
      float sd = 0.f;
      #pragma unroll
      for (int f = 0; f < F_; ++f) sd += q[f] * Kh[m * 17 + f];
      sd *= 0.25f;
      sc[m] = sd;
      mx = fmaxf(mx, sd);
    }
    float den = 0.f;
    for (int m = 0; m < N_; ++m) { sc[m] = __expf(sc[m] - mx); den += sc[m]; }
    float inv = 1.f / den;
    #pragma unroll
    for (int f = 0; f < F_; ++f) o[f] = 0.f;
    const float* Vh = &Vs[h * 409];
    for (int m = 0; m < N_; ++m) {
      float p = sc[m] * inv;
      #pragma unroll
      for (int f = 0; f < F_; ++f) o[f] += p * Vh[m * 17 + f];
    }
    {
      const ushort* xp = Xb + (size_t)row * ND_ + cbase;
      union { uint4 u[2]; ushort s[16]; } xu;
      xu.u[0] = *(const uint4*)xp;
      xu.u[1] = *(const uint4*)(xp + 8);
      #pragma unroll
      for (int f = 0; f < F_; ++f) {
        float v = o[f] + bf2f(xu.s[f]);
        o[f] = v;
        s += v;
        s2 += v * v;
      }
    }
  }
  #pragma unroll
  for (int m = 1; m < 64; m <<= 1) {
    s += __shfl_xor(s, m, 64);
    s2 += __shfl_xor(s2, m, 64);
  }
  int w = tid >> 6;
  if ((tid & 63) == 0) { ps[w] = s; ps2[w] = s2; }
  __syncthreads();
  float ts = ps[0] + ps[1] + ps[2] + ps[3];
  float ts2 = ps2[0] + ps2[1] + ps2[2] + ps2[3];
  float mu = ts / (float)ND_;
  float var = ts2 / (float)ND_ - mu * mu;
  float rs = rsqrtf(var + 1e-5f);
  if (tid < 192) {
    union { uint4 u[2]; ushort s[16]; } ov;
    #pragma unroll
    for (int f = 0; f < F_; ++f)
      ov.s[f] = f2bf((o[f] - mu) * rs * g[cbase + f] + be[cbase + f]);
    ushort* op = T2b + (size_t)row * ND_ + cbase;
    *(uint4*)op = ov.u[0];
    *(uint4*)(op + 8) = ov.u[1];
  }
}

// ---------------- temporal attention via MFMA, transposed layout ------------------
__global__ __launch_bounds__(256) void k_temporal_mfma(const ushort* __restrict__ tQ,
                                                       const ushort* __restrict__ tK,
                                                       const ushort* __restrict__ tV,
                                                       ushort* __restrict__ Ob)
{
  long long gb = (long long)blockIdx.x * (T_ * F_);
  int tid = threadIdx.x;
  __shared__ ushort Kl[T_][20];
  __shared__ ushort Ql[T_][20];
  __shared__ ushort Vt[F_][200];
  {
    const uint4* Kg4 = (const uint4*)(tK + gb);
    const uint4* Qg4 = (const uint4*)(tQ + gb);
    const uint4* Vg4 = (const uint4*)(tV + gb);
    for (int task = tid; task < 1152; task += 256) {
      int ten = task / 384, idx = task - ten * 384;
      int t = idx >> 1, half = idx & 1;
      if (ten == 0) {
        uint4 v = Kg4[idx];
        *(uint2*)&Kl[t][half * 8] = make_uint2(v.x, v.y);
        *(uint2*)&Kl[t][half * 8 + 4] = make_uint2(v.z, v.w);
      } else if (ten == 1) {
        uint4 v = Qg4[idx];
        *(uint2*)&Ql[t][half * 8] = make_uint2(v.x, v.y);
        *(uint2*)&Ql[t][half * 8 + 4] = make_uint2(v.z, v.w);
      } else {
        union { uint4 u4; ushort s[8]; } vv;
        vv.u4 = Vg4[idx];
        #pragma unroll
        for (int f = 0; f < 8; ++f) Vt[half * 8 + f][t] = vv.s[f];
      }
    }
  }
  __syncthreads();
  int lane = tid & 63, wid = tid >> 6;
  int lr = lane & 15, lg = lane >> 4;
  const bf16x4_t z4 = (bf16x4_t){0, 0, 0, 0};
  const f32x4_t zf = (f32x4_t){0.f, 0.f, 0.f, 0.f};
  #pragma unroll
  for (int jj = 0; jj < 3; ++jj) {
    int q0 = (wid * 3 + jj) * 16;
    union { bf16x8_t v; bf16x4_t h4[2]; } qf;
    qf.h4[0] = *(const bf16x4_t*)&Ql[q0 + lr][lg * 4];
    qf.h4[1] = z4;
    f32x4_t d[12];
    #pragma unroll
    for (int i = 0; i < 12; ++i) {
      union { bf16x8_t v; bf16x4_t h4[2]; } kf;
      kf.h4[0] = *(const bf16x4_t*)&Kl[i * 16 + lr][lg * 4];
      kf.h4[1] = z4;
      d[i] = __builtin_amdgcn_mfma_f32_16x16x32_bf16(kf.v, qf.v, zf, 0, 0, 0);
    }
    int qg = q0 + lr;
    float lsum = 0.f;
    #pragma unroll
    for (int i = 0; i < 12; ++i) {
      #pragma unroll
      for (int r = 0; r < 4; ++r) {
        int k = i * 16 + lg * 4 + r;
        float p = __expf(d[i][r] * 0.25f + ((k < qg) ? 1.0f : 0.0f));
        d[i][r] = p;
        lsum += p;
      }
    }
    lsum += __shfl_xor(lsum, 16, 64);
    lsum += __shfl_xor(lsum, 32, 64);
    f32x4_t o = zf;
    #pragma unroll
    for (int i = 0; i < 6; ++i) {
      union { bf16x8_t v; bf16x4_t h4[2]; } vf;
      vf.h4[0] = *(const bf16x4_t*)&Vt[lr][i * 32 + lg * 4];
      vf.h4[1] = *(const bf16x4_t*)&Vt[lr][i * 32 + 16 + lg * 4];
      union { bf16x8_t v; uint uu[4]; } pf;
      pf.uu[0] = cvtpk(d[2 * i][0], d[2 * i][1]);
      pf.uu[1] = cvtpk(d[2 * i][2], d[2 * i][3]);
      pf.uu[2] = cvtpk(d[2 * i + 1][0], d[2 * i + 1][1]);
      pf.uu[3] = cvtpk(d[2 * i + 1][2], d[2 * i + 1][3]);
      o = __builtin_amdgcn_mfma_f32_16x16x32_bf16(vf.v, pf.v, o, 0, 0, 0);
    }
    float inv = 1.f / lsum;
    bf16x4_t ov;
    #pragma unroll
    for (int r = 0; r < 4; ++r) ov[r] = (short)f2bf(o[r] * inv);
    *(bf16x4_t*)(Ob + gb + (long long)qg * F_ + lg * 4) = ov;
  }
}

// ---------------- Ab = T2b + LN(Opjb + Xb)  (register-resident, no LDS buf) -------
__global__ __launch_bounds__(256) void k_lnres_add(const ushort* __restrict__ Ain,
                                                   const ushort* __restrict__ Xb,
                                                   const ushort* __restrict__ T2,
                                                   const float* __restrict__ g,
                                                   const float* __restrict__ be,
                                                   ushort* __restrict__ Ab)
{
  int row = blockIdx.x;
  int tid = threadIdx.x;
  __shared__ float ps[4], ps2[4];
  const uint4* Ar = (const uint4*)(Ain + (size_t)row * ND_);
  const uint4* Xr = (const uint4*)(Xb + (size_t)row * ND_);
  float v0[8], v1[8];
  float s = 0.f, s2 = 0.f;
  {
    uint4 av = Ar[tid], xv = Xr[tid];
    const ushort* ap = (const ushort*)&av;
    const ushort* xp = (const ushort*)&xv;
    #pragma unroll
    for (int j = 0; j < 8; ++j) {
      float v = bf2f(ap[j]) + bf2f(xp[j]);
      v0[j] = v;
      s += v;
      s2 += v * v;
    }
  }
  if (tid < 128) {
    uint4 av = Ar[tid + 256], xv = Xr[tid + 256];
    const ushort* ap = (const ushort*)&av;
    const ushort* xp = (const ushort*)&xv;
    #pragma unroll
    for (int j = 0; j < 8; ++j) {
      float v = bf2f(ap[j]) + bf2f(xp[j]);
      v1[j] = v;
      s += v;
      s2 += v * v;
    }
  }
  #pragma unroll
  for (int m = 1; m < 64; m <<= 1) {
    s += __shfl_xor(s, m, 64);
    s2 += __shfl_xor(s2, m, 64);
  }
  int w = tid >> 6;
  if ((tid & 63) == 0) { ps[w] = s; ps2[w] = s2; }
  __syncthreads();
  float ts = ps[0] + ps[1] + ps[2] + ps[3];
  float ts2 = ps2[0] + ps2[1] + ps2[2] + ps2[3];
  float mu = ts / (float)ND_;
  float var = ts2 / (float)ND_ - mu * mu;
  float rs = rsqrtf(var + 1e-5f);
  const uint4* Tr = (const uint4*)(T2 + (size_t)row * ND_);
  uint4* Or = (uint4*)(Ab + (size_t)row * ND_);
  {
    uint4 tv = Tr[tid];
    const ushort* tp = (const ushort*)&tv;
    uint4 ov;
    ushort* op = (ushort*)&ov;
    int i0 = tid * 8;
    #pragma unroll
    for (int j = 0; j < 8; ++j)
      op[j] = f2bf((v0[j] - mu) * rs * g[i0 + j] + be[i0 + j] + bf2f(tp[j]));
    Or[tid] = ov;
  }
  if (tid < 128) {
    uint4 tv = Tr[tid + 256];
    const ushort* tp = (const ushort*)&tv;
    uint4 ov;
    ushort* op = (ushort*)&ov;
    int i0 = (tid + 256) * 8;
    #pragma unroll
    for (int j = 0; j < 8; ++j)
      op[j] = f2bf((v1[j] - mu) * rs * g[i0 + j] + be[i0 + j] + bf2f(tp[j]));
    Or[tid + 256] = ov;
  }
}

// ---------------- final projection + input residual ----------------
__global__ __launch_bounds__(256) void k_final(const ushort* __restrict__ Xb,
                                               const float* __restrict__ Wf,
                                               const float* __restrict__ bf,
                                               const float* __restrict__ in,
                                               float* __restrict__ out)
{
  int row = blockIdx.x;   // t*B + b
  int t = row / B_, b = row % B_;
  int tid = threadIdx.x;
  __shared__ float xr[ND_];
  const uint4* Xr = (const uint4*)(Xb + (size_t)row * ND_);
  for (int i8 = tid; i8 < ND_ / 8; i8 += 256) {
    uint4 xv = Xr[i8];
    const ushort* xp = (const ushort*)&xv;
    #pragma unroll
    for (int j = 0; j < 8; ++j) xr[i8 * 8 + j] = bf2f(xp[j]);
  }
  __syncthreads();
  if (tid < N_ * M_) {
    int n = tid / M_, mm = tid % M_;
    float acc = bf[mm];
    for (int d = 0; d < D_; ++d) acc += xr[n * D_ + d] * Wf[(size_t)d * M_ + mm];
    size_t oi = ((size_t)b * T_ + t) * (N_ * M_) + tid;
    out[oi] = acc + in[oi];
  }
}

extern "C" void kernel_launch(void* const* d_in, const int* in_sizes, int n_in,
                              void* d_out, int out_size, void* d_ws, size_t ws_size,
                              hipStream_t stream)
{
  const float* inputs = (const float*)d_in[0];
  const float* emb_W  = (const float*)d_in[1];
  const float* emb_b  = (const float*)d_in[2];
  const float* sa_Wq  = (const float*)d_in[3];
  const float* sa_bq  = (const float*)d_in[4];
  const float* sa_Wk  = (const float*)d_in[5];
  const float* sa_bk  = (const float*)d_in[6];
  const float* sa_Wv  = (const float*)d_in[7];
  const float* sa_bv  = (const float*)d_in[8];
  const float* ta_Wq  = (const float*)d_in[9];
  const float* ta_bq  = (const float*)d_in[10];
  const float* ta_Wk  = (const float*)d_in[11];
  const float* ta_bk  = (const float*)d_in[12];
  const float* ta_Wv  = (const float*)d_in[13];
  const float* ta_bv  = (const float*)d_in[14];
  const float* ta_Wo  = (const float*)d_in[15];
  const float* ta_bo  = (const float*)d_in[16];
  const float* ln_g   = (const float*)d_in[17];
  const float* ln_b   = (const float*)d_in[18];
  const float* lns_g  = (const float*)d_in[19];
  const float* lns_b  = (const float*)d_in[20];
  const float* ff_W1  = (const float*)d_in[21];
  const float* ff_b1  = (const float*)d_in[22];
  const float* ff_W2  = (const float*)d_in[23];
  const float* ff_b2  = (const float*)d_in[24];
  const float* fin_W  = (const float*)d_in[25];
  const float* fin_b  = (const float*)d_in[26];
  float* out = (float*)d_out;

  // ---- workspace layout ----
  char* base = (char*)d_ws;
  ushort* Xb  = (ushort*)base;                       // [0, 2SZ)
  ushort* C0  = (ushort*)(base + 2 * SZ_);           // [2SZ, 14SZ): slots S0..S5
  ushort* T2b = (ushort*)(base + 14 * SZ_);          // [14SZ, 16SZ)
  ushort* sQ = C0;                       // S0
  ushort* sK = C0 + SZ_;                 // S1
  ushort* sV = C0 + 2 * SZ_;             // S2
  ushort* tQ = C0 + 3 * SZ_;             // S3 (transposed layout)
  ushort* tK = C0 + 4 * SZ_;             // S4 (transposed layout)
  ushort* tV = C0 + 5 * SZ_;             // S5 (transposed layout)
  ushort* AOb  = tV;                     // temporal attn writes S5 in place
  ushort* Opjb = sQ;                     // oproj out -> S0
  ushort* Ab   = sK;                     // lnres_add out -> S1
  ushort* hB   = tK;                     // FF hidden -> S4+S5

  ushort* wts = (ushort*)(base + 16 * SZ_);          // 2 layers x WL_
  float* fb   = (float*)(wts + 2 * WL_);             // 2 layers x 3328
  float* peT  = fb + 2 * 3328;                       // 589824

  // ---- both layers' weight packing (fragment layout), hoisted ----
  k_pack_sp<<<dim3(1677, 2), 256, 0, stream>>>(sa_Wq, sa_bq, sa_Wk, sa_bk,
                                               sa_Wv, sa_bv, wts, fb);
  PackWArgs pw;
  pw.src[0] = ta_Wq; pw.src[1] = ta_Wk; pw.src[2] = ta_Wv; pw.src[3] = ta_Wo;
  pw.src[4] = ff_W1; pw.src[5] = ff_W2;
  pw.wts = wts;
  k_pack_w<<<dim3(400, 2), 256, 0, stream>>>(pw);

  k_pe<<<(T_ * ND_ + 255) / 256, 256, 0, stream>>>(peT);
  k_embed<<<ROWS_, 256, 0, stream>>>(inputs, emb_W, emb_b, peT, Xb);

  for (int l = 0; l < 2; ++l) {
    ushort* wl = wts + (long long)l * WL_;
    ushort* sWq = wl;
    ushort* sWk = wl + 393216;
    ushort* sWv = wl + 409600;
    ushort* tWq = wl + 425984;
    ushort* tWk = wl + 819200;
    ushort* tWv = wl + 1212416;
    ushort* tWo = wl + 1605632;
    ushort* W1t = wl + 1998848;
    ushort* W2t = wl + 2031616;
    float* fl = fb + l * 3328;
    float* bqP = fl;
    float* bkP = fl + 3072;
    float* bvP = fl + 3200;

    Qkv6Args qa;
    qa.W[0] = sWk; qa.bias[0] = bkP;                         qa.C[0] = sK;
    qa.wGroup[0] = 0;     qa.biasGroup[0] = 0;   qa.tpose[0] = 0;
    qa.W[1] = sWv; qa.bias[1] = bvP;                         qa.C[1] = sV;
    qa.wGroup[1] = 0;     qa.biasGroup[1] = 0;   qa.tpose[1] = 0;
    qa.W[2] = sWq; qa.bias[2] = bqP;                         qa.C[2] = sQ;
    qa.wGroup[2] = 16384; qa.biasGroup[2] = 128; qa.tpose[2] = 0;
    qa.W[3] = tWq; qa.bias[3] = ta_bq + (size_t)l * N_ * D_; qa.C[3] = tQ;
    qa.wGroup[3] = 16384; qa.biasGroup[3] = 128; qa.tpose[3] = 1;
    qa.W[4] = tWk; qa.bias[4] = ta_bk + (size_t)l * N_ * D_; qa.C[4] = tK;
    qa.wGroup[4] = 16384; qa.biasGroup[4] = 128; qa.tpose[4] = 1;
    qa.W[5] = tWv; qa.bias[5] = ta_bv + (size_t)l * N_ * D_; qa.C[5] = tV;
    qa.wGroup[5] = 16384; qa.biasGroup[5] = 128; qa.tpose[5] = 1;
    k_qkv6<<<dim3(ROWS_ / 128, 6, N_), 256, 0, stream>>>(Xb, qa);

    k_spatial_ln<<<ROWS_, 256, 0, stream>>>(sQ, sK, sV, Xb, ln_g + (size_t)l * ND_,
                                            ln_b + (size_t)l * ND_, T2b);

    k_temporal_mfma<<<B_ * N_ * H_, 256, 0, stream>>>(tQ, tK, tV, AOb);
    k_oproj<<<dim3(ROWS_ / 128, 1, N_), 256, 0, stream>>>(
        AOb, tWo, ta_bo + (size_t)l * N_ * D_, Opjb);

    k_lnres_add<<<ROWS_, 256, 0, stream>>>(Opjb, Xb, T2b, ln_g + (size_t)l * ND_,
                                           ln_b + (size_t)l * ND_, Ab);

    k_ff1<<<dim3(ROWS_ * N_ / 128, 2, 1), 256, 0, stream>>>(
        Ab, W1t, ff_b1 + (size_t)l * FF_, hB);
    k_ff2_ln<<<dim3(ROWS_ * N_ / 128, 1, 1), 256, 0, stream>>>(
        hB, W2t, ff_b2 + (size_t)l * D_, Ab,
        lns_g + (size_t)l * D_, lns_b + (size_t)l * D_, Xb);
  }

  k_final<<<ROWS_, 256, 0, stream>>>(Xb, fin_W, fin_b, inputs, out);
}

// Round 24
// 426.403 us; speedup vs baseline: 1.1541x; 1.1541x over previous
//
#include <hip/hip_runtime.h>
#include <cmath>

namespace {
constexpr int B_ = 16, T_ = 192, N_ = 24, D_ = 128, M_ = 9, H_ = 8, F_ = 16, FF_ = 256;
constexpr int ND_ = N_ * D_;                       // 3072
constexpr int ROWS_ = T_ * B_;                     // 3072
constexpr long long SZ_ = (long long)ROWS_ * ND_;  // 9437184 elements
constexpr long long WL_ = 2064384;                 // ushorts per layer weight area
}

typedef __attribute__((ext_vector_type(8))) short bf16x8_t;
typedef __attribute__((ext_vector_type(4))) short bf16x4_t;
typedef __attribute__((ext_vector_type(4))) float f32x4_t;

static __device__ __forceinline__ ushort f2bf(float f) {
  union { float f; uint u; } v; v.f = f;
  uint r = v.u + 0x7fffu + ((v.u >> 16) & 1u);   // RNE
  return (ushort)(r >> 16);
}
static __device__ __forceinline__ float bf2f(ushort u) {
  union { uint u; float f; } v; v.u = ((uint)u) << 16; return v.f;
}
static __device__ __forceinline__ uint cvtpk(float lo, float hi) {
  uint r;
  asm("v_cvt_pk_bf16_f32 %0, %1, %2" : "=v"(r) : "v"(lo), "v"(hi));
  return r;
}
// fragment-major index, SIGMA slot permutation: slot(lg,rem) holds k = kq*32+lg*8+rem
static __device__ __forceinline__ int fragIdx(int e, int k, int KQ) {
  int n = e >> 4, lr = e & 15;
  int kq = k >> 5, kr = k & 31;
  int lg = kr >> 3, rem = kr & 7;
  return (((n * KQ + kq) * 64 + lg * 16 + lr) << 3) + rem;
}

// ---------------- positional-encoding table: pe[t][c], 192x3072 ----------------
__global__ __launch_bounds__(256) void k_pe(float* __restrict__ pe)
{
  int i = blockIdx.x * 256 + threadIdx.x;
  if (i >= T_ * ND_) return;
  int t = i / ND_, c = i % ND_;
  float freq = expf((float)(2 * (c >> 1)) * (-9.210340371976184f / 3072.0f));
  float ang = (float)t * freq;
  pe[i] = (c & 1) ? cosf(ang) : sinf(ang);
}

// ---------------- embedding + PE -> bf16 X ----------------
__global__ __launch_bounds__(256) void k_embed(const float* __restrict__ in,
                                               const float* __restrict__ Wemb,
                                               const float* __restrict__ bemb,
                                               const float* __restrict__ pe,
                                               ushort* __restrict__ Xb)
{
  int row = blockIdx.x;            // t*B + b
  int t = row / B_, b = row % B_;
  int tid = threadIdx.x;
  __shared__ float inr[N_ * M_];
  const float* ip = in + ((size_t)b * T_ + t) * (N_ * M_);
  if (tid < N_ * M_) inr[tid] = ip[tid];
  __syncthreads();
  uint* Xr = (uint*)(Xb + (size_t)row * ND_);
  const float* per = pe + (size_t)t * ND_;
  for (int cc = tid; cc < ND_ / 2; cc += 256) {
    int c = cc * 2;
    int n = c >> 7;
    int d = c & 127;
    const float* xr = &inr[n * M_];
    float a0 = bemb[n * D_ + d] + per[c];
    float a1 = bemb[n * D_ + d + 1] + per[c + 1];
    const float* wp = Wemb + (size_t)(n * M_) * D_ + d;
    #pragma unroll
    for (int m = 0; m < M_; ++m) {
      float xm = xr[m];
      a0 += xm * wp[(size_t)m * D_];
      a1 += xm * wp[(size_t)m * D_ + 1];
    }
    Xr[cc] = (uint)f2bf(a0) | ((uint)f2bf(a1) << 16);
  }
}

// ---------------- spatial weight/bias packing, FRAGMENT layout (sigma) ----------
__global__ __launch_bounds__(256) void k_pack_sp(const float* __restrict__ saWq,
                                                 const float* __restrict__ sabq,
                                                 const float* __restrict__ saWk,
                                                 const float* __restrict__ sabk,
                                                 const float* __restrict__ saWv,
                                                 const float* __restrict__ sabv,
                                                 ushort* __restrict__ wts,
                                                 float* __restrict__ fb)
{
  int l = blockIdx.y;
  int i = blockIdx.x * 256 + threadIdx.x;
  ushort* wl = wts + (long long)l * WL_;
  float* fl = fb + l * 3328;
  if (i < 393216) {                       // sWq frag: per joint gz, tile 128x128
    int gz = i >> 14, il = i & 16383;
    int j = il & 7;
    int lane = (il >> 3) & 63;
    int nk = il >> 9;                     // n*4+kq
    int kq = nk & 3, n8 = nk >> 2;
    int lr = lane & 15, lg = lane >> 4;
    int e = n8 * 16 + lr;
    int d = kq * 32 + lg * 8 + j;
    int h = e >> 4, f = e & 15;
    wl[i] = f2bf(saWq[(long long)l * 393216 + (((size_t)h * N_ + gz) * D_ + d) * F_ + f]);
  } else if (i < 409600) {                // sWk frag: tile 128x128
    int il = i - 393216;
    int j = il & 7;
    int lane = (il >> 3) & 63;
    int nk = il >> 9;
    int kq = nk & 3, n8 = nk >> 2;
    int lr = lane & 15, lg = lane >> 4;
    int e = n8 * 16 + lr;
    int d = kq * 32 + lg * 8 + j;
    int h = e >> 4, f = e & 15;
    wl[i] = f2bf(saWk[(long long)l * 16384 + ((size_t)h * D_ + d) * F_ + f]);
  } else if (i < 425984) {                // sWv frag
    int il = i - 409600;
    int j = il & 7;
    int lane = (il >> 3) & 63;
    int nk = il >> 9;
    int kq = nk & 3, n8 = nk >> 2;
    int lr = lane & 15, lg = lane >> 4;
    int e = n8 * 16 + lr;
    int d = kq * 32 + lg * 8 + j;
    int h = e >> 4, f = e & 15;
    wl[i] = f2bf(saWv[(long long)l * 16384 + ((size_t)h * D_ + d) * F_ + f]);
  } else if (i < 429056) {                // bqP[n][e]
    int j = i - 425984;
    int n = j >> 7, e = j & 127, h = e >> 4, f = e & 15;
    fl[j] = sabq[l * 3072 + ((size_t)h * N_ + n) * F_ + f];
  } else if (i < 429184) {
    int j = i - 429056, h = j >> 4, f = j & 15;
    fl[3072 + j] = sabk[l * 128 + h * F_ + f];
  } else if (i < 429312) {
    int j = i - 429184, h = j >> 4, f = j & 15;
    fl[3200 + j] = sabv[l * 128 + h * F_ + f];
  }
}

// ---------------- transposed weight packing -> FRAGMENT layout -------------------
struct PackWArgs {
  const float* src[6];     // layer-0 bases: taWq, taWk, taWv, taWo, ffW1, ffW2
  ushort* wts;
};
__global__ __launch_bounds__(256) void k_pack_w(PackWArgs args)
{
  __shared__ float tile[64][65];
  int l = blockIdx.y;
  int x = blockIdx.x;
  ushort* wl = args.wts + (long long)l * WL_;
  const float* sp; ushort* dp;
  int bx, by, Rr, Cc, mode;
  if (x < 384) {
    int ten = x / 96, rem = x % 96, g = rem / 4, tl = rem % 4;
    bx = tl & 1; by = tl >> 1; Rr = 128; Cc = 128; mode = 0;
    sp = args.src[ten] + (long long)l * 393216 + (long long)g * 16384;
    dp = wl + 425984 + (long long)ten * 393216 + (long long)g * 16384;
  } else if (x < 392) {
    int idx = x - 384; bx = idx & 3; by = idx >> 2; Rr = 128; Cc = 256; mode = 1;
    sp = args.src[4] + (long long)l * 32768;
    dp = wl + 1998848;
  } else {
    int idx = x - 392; bx = idx & 1; by = idx >> 1; Rr = 256; Cc = 128; mode = 2;
    sp = args.src[5] + (long long)l * 32768;
    dp = wl + 2031616;
  }
  int c0 = bx * 64, r0 = by * 64;
  int ci = threadIdx.x & 63, rq = threadIdx.x >> 6;
  #pragma unroll
  for (int k = 0; k < 16; ++k) {
    int r = rq * 16 + k;
    tile[r][ci] = sp[(long long)(r0 + r) * Cc + c0 + ci];
  }
  __syncthreads();
  int ri = threadIdx.x & 63, cq = threadIdx.x >> 6;
  #pragma unroll
  for (int k = 0; k < 16; ++k) {
    int c = cq * 16 + k;
    int eg = c0 + c;          // output-col (e) dim
    int kg = r0 + ri;         // k dim
    int idx;
    if (mode == 1)      idx = (eg >> 7) * 16384 + fragIdx(eg & 127, kg, 4);
    else if (mode == 2) idx = fragIdx(eg, kg, 8);
    else                idx = fragIdx(eg, kg, 4);
    dp[idx] = f2bf(tile[ri][c]);
  }
}

// ---------------- unified 6-projection MFMA GEMM (2 row-tiles/block) ------------
struct Qkv6Args {
  const ushort* W[6];
  const float* bias[6];
  ushort* C[6];
  long long wGroup[6];
  int biasGroup[6];
  int tpose[6];
};
__global__ __launch_bounds__(256) void k_qkv6(const ushort* __restrict__ A, Qkv6Args args)
{
  __shared__ ushort Wl[16384];          // 32 KB, flat fragment layout
  int p = blockIdx.y;
  int gz = blockIdx.z;
  int tid = threadIdx.x;
  int lane = tid & 63, wid = tid >> 6;
  int lr = lane & 15, lg = lane >> 4;
  {
    const ushort* Wf = args.W[p] + (long long)gz * args.wGroup[p];
    #pragma unroll
    for (int it = 0; it < 8; ++it) {
      int idx = (it * 256 + tid) << 3;
      *(uint4*)&Wl[idx] = *(const uint4*)(Wf + idx);
    }
  }
  __syncthreads();
  const float* bb = args.bias[p] + (long long)gz * args.biasGroup[p];
  #pragma unroll
  for (int tt = 0; tt < 2; ++tt) {
    int row0 = (blockIdx.x * 2 + tt) * 64 + wid * 16;
    bf16x8_t au[4];
    {
      const ushort* ap = A + (long long)gz * 128 + (long long)(row0 + lr) * ND_ + lg * 8;
      #pragma unroll
      for (int kq = 0; kq < 4; ++kq)
        au[kq] = *(const bf16x8_t*)(ap + kq * 32);
    }
    f32x4_t acc[8];
    #pragma unroll
    for (int n = 0; n < 8; ++n) acc[n] = (f32x4_t){0.f, 0.f, 0.f, 0.f};
    #pragma unroll
    for (int n = 0; n < 8; ++n) {
      #pragma unroll
      for (int kq = 0; kq < 4; ++kq) {
        bf16x8_t bu = *(const bf16x8_t*)&Wl[((n * 4 + kq) * 64 + lane) << 3];
        acc[n] = __builtin_amdgcn_mfma_f32_16x16x32_bf16(au[kq], bu, acc[n], 0, 0, 0);
      }
    }
    if (args.tpose[p]) {
      ushort* Cp = args.C[p];
      #pragma unroll
      for (int n = 0; n < 8; ++n) {
        float bv = bb[n * 16 + lr];
        #pragma unroll
        for (int r = 0; r < 4; ++r) {
          int rg = row0 + lg * 4 + r;
          int ttg = rg >> 4, bI = rg & 15;
          long long gI = ((long long)bI * N_ + gz) * H_ + n;
          Cp[(gI * T_ + ttg) * F_ + lr] = f2bf(acc[n][r] + bv);
        }
      }
    } else {
      ushort* Cp = args.C[p] + (long long)gz * 128;
      #pragma unroll
      for (int n = 0; n < 8; ++n) {
        float bv = bb[n * 16 + lr];
        #pragma unroll
        for (int r = 0; r < 4; ++r)
          Cp[(long long)(row0 + lg * 4 + r) * ND_ + n * 16 + lr] = f2bf(acc[n][r] + bv);
      }
    }
  }
}

// ---------------- FF1 (flat-LDS frag staging), relu -> bf16 out ----------------
__global__ __launch_bounds__(256) void k_ff1(
    const ushort* __restrict__ A, const ushort* __restrict__ Wt,
    const float* __restrict__ bias, ushort* __restrict__ Cout)
{
  __shared__ ushort Wl[16384];
  int tid = threadIdx.x;
  int lane = tid & 63, wid = tid >> 6;
  int lr = lane & 15, lg = lane >> 4;
  int row0 = blockIdx.x * 64 + wid * 16;
  {
    const ushort* Wf = Wt + (long long)blockIdx.y * 16384;
    #pragma unroll
    for (int it = 0; it < 8; ++it) {
      int idx = (it * 256 + tid) << 3;
      *(uint4*)&Wl[idx] = *(const uint4*)(Wf + idx);
    }
  }
  bf16x8_t au[4];
  {
    const ushort* ap = A + (long long)(row0 + lr) * 128 + lg * 8;
    #pragma unroll
    for (int kq = 0; kq < 4; ++kq)
      au[kq] = *(const bf16x8_t*)(ap + kq * 32);
  }
  __syncthreads();
  f32x4_t acc[8];
  #pragma unroll
  for (int n = 0; n < 8; ++n) acc[n] = (f32x4_t){0.f, 0.f, 0.f, 0.f};
  #pragma unroll
  for (int n = 0; n < 8; ++n) {
    #pragma unroll
    for (int kq = 0; kq < 4; ++kq) {
      bf16x8_t bu = *(const bf16x8_t*)&Wl[((n * 4 + kq) * 64 + lane) << 3];
      acc[n] = __builtin_amdgcn_mfma_f32_16x16x32_bf16(au[kq], bu, acc[n], 0, 0, 0);
    }
  }
  const float* bb = bias + blockIdx.y * 128;
  int ccolBase = blockIdx.y * 128 + lr;
  #pragma unroll
  for (int n = 0; n < 8; ++n) {
    float bv = bb[n * 16 + lr];
    #pragma unroll
    for (int r = 0; r < 4; ++r) {
      float v = fmaxf(acc[n][r] + bv, 0.f);
      Cout[(long long)(row0 + lg * 4 + r) * 256 + ccolBase + n * 16] = f2bf(v);
    }
  }
}

// ---------------- FF2 + residual + per-joint LN_128 fused -> Xb ----------------
__global__ __launch_bounds__(256) void k_ff2_ln(
    const ushort* __restrict__ A,      // hB: 73728 x 256
    const ushort* __restrict__ Wt,     // W2 frag layout (KQ=8)
    const float* __restrict__ bias,    // ff_b2 (128)
    const ushort* __restrict__ Res,    // Ab flat 73728 x 128
    const float* __restrict__ g,       // lns_g (128)
    const float* __restrict__ be,      // lns_b (128)
    ushort* __restrict__ Xb)           // flat 73728 x 128
{
  __shared__ ushort Wl[32768];          // 64 KB, flat fragment layout
  int tid = threadIdx.x;
  int lane = tid & 63, wid = tid >> 6;
  int lr = lane & 15, lg = lane >> 4;
  int row0 = blockIdx.x * 64 + wid * 16;
  {
    #pragma unroll
    for (int it = 0; it < 16; ++it) {
      int idx = (it * 256 + tid) << 3;
      *(uint4*)&Wl[idx] = *(const uint4*)(Wt + idx);
    }
  }
  bf16x8_t au[8];
  {
    const ushort* ap = A + (long long)(row0 + lr) * 256 + lg * 8;
    #pragma unroll
    for (int kq = 0; kq < 8; ++kq)
      au[kq] = *(const bf16x8_t*)(ap + kq * 32);
  }
  __syncthreads();
  f32x4_t acc[8];
  #pragma unroll
  for (int n = 0; n < 8; ++n) acc[n] = (f32x4_t){0.f, 0.f, 0.f, 0.f};
  #pragma unroll
  for (int n = 0; n < 8; ++n) {
    #pragma unroll
    for (int kq = 0; kq < 8; ++kq) {
      bf16x8_t bu = *(const bf16x8_t*)&Wl[((n * 8 + kq) * 64 + lane) << 3];
      acc[n] = __builtin_amdgcn_mfma_f32_16x16x32_bf16(au[kq], bu, acc[n], 0, 0, 0);
    }
  }
  // epilogue: + bias + residual, per-row LN over 128
  float s[4] = {0.f, 0.f, 0.f, 0.f};
  float s2[4] = {0.f, 0.f, 0.f, 0.f};
  #pragma unroll
  for (int n = 0; n < 8; ++n) {
    float bv = bias[n * 16 + lr];
    #pragma unroll
    for (int r = 0; r < 4; ++r) {
      float v = acc[n][r] + bv
              + bf2f(Res[(long long)(row0 + lg * 4 + r) * 128 + n * 16 + lr]);
      acc[n][r] = v;
      s[r] += v;
      s2[r] += v * v;
    }
  }
  #pragma unroll
  for (int m = 1; m < 16; m <<= 1) {
    #pragma unroll
    for (int r = 0; r < 4; ++r) {
      s[r] += __shfl_xor(s[r], m, 64);
      s2[r] += __shfl_xor(s2[r], m, 64);
    }
  }
  #pragma unroll
  for (int r = 0; r < 4; ++r) {
    float mu = s[r] * (1.f / 128.f);
    float var = s2[r] * (1.f / 128.f) - mu * mu;
    float rs = rsqrtf(var + 1e-5f);
    long long rb = (long long)(row0 + lg * 4 + r) * 128;
    #pragma unroll
    for (int n = 0; n < 8; ++n) {
      int col = n * 16 + lr;
      Xb[rb + col] = f2bf((acc[n][r] - mu) * rs * g[col] + be[col]);
    }
  }
}

// ---------------- oproj (flat-LDS frag staging); A transposed TT layout ----------
__global__ __launch_bounds__(256) void k_oproj(const ushort* __restrict__ A,
                                               const ushort* __restrict__ Wt,
                                               const float* __restrict__ bias,
                                               ushort* __restrict__ Cout)
{
  __shared__ ushort Wl[16384];
  int gz = blockIdx.z;
  int tid = threadIdx.x;
  int lane = tid & 63, wid = tid >> 6;
  int lr = lane & 15, lg = lane >> 4;
  int row0 = blockIdx.x * 64 + wid * 16;   // multiple of 16 -> t uniform, b = lr
  int tW = row0 >> 4;
  {
    const ushort* Wf = Wt + (long long)gz * 16384;
    #pragma unroll
    for (int it = 0; it < 8; ++it) {
      int idx = (it * 256 + tid) << 3;
      *(uint4*)&Wl[idx] = *(const uint4*)(Wf + idx);
    }
  }
  union { bf16x8_t v; bf16x4_t h[2]; } au[4];
  {
    // sigma layout: slot(lg, hi*4+j) holds k = kq*32 + lg*8 + hi*4 + j
    // k -> h = 2*kq + (lg>>1), f = (lg&1)*8 + hi*4 + j
    const ushort* ab = A + (((long long)lr * N_ + gz) * H_ + (lg >> 1)) * ((long long)T_ * F_)
                         + (long long)tW * F_ + (lg & 1) * 8;
    #pragma unroll
    for (int kq = 0; kq < 4; ++kq) {
      au[kq].h[0] = *(const bf16x4_t*)(ab + (long long)(2 * kq) * (T_ * F_));
      au[kq].h[1] = *(const bf16x4_t*)(ab + (long long)(2 * kq) * (T_ * F_) + 4);
    }
  }
  __syncthreads();
  f32x4_t acc[8];
  #pragma unroll
  for (int n = 0; n < 8; ++n) acc[n] = (f32x4_t){0.f, 0.f, 0.f, 0.f};
  #pragma unroll
  for (int n = 0; n < 8; ++n) {
    #pragma unroll
    for (int kq = 0; kq < 4; ++kq) {
      bf16x8_t bu = *(const bf16x8_t*)&Wl[((n * 4 + kq) * 64 + lane) << 3];
      acc[n] = __builtin_amdgcn_mfma_f32_16x16x32_bf16(au[kq].v, bu, acc[n], 0, 0, 0);
    }
  }
  const float* bb = bias + (long long)gz * 128;
  ushort* C = Cout + (long long)gz * 128;
  #pragma unroll
  for (int n = 0; n < 8; ++n) {
    float bv = bb[n * 16 + lr];
    #pragma unroll
    for (int r = 0; r < 4; ++r)
      C[(long long)(row0 + lg * 4 + r) * ND_ + n * 16 + lr] = f2bf(acc[n][r] + bv);
  }
}

// ---------------- fused spatial attention + LN -> T2b, register-resident O --------
__global__ __launch_bounds__(256) void k_spatial_ln(const ushort* __restrict__ Qg,
                                                    const ushort* __restrict__ Kg,
                                                    const ushort* __restrict__ Vg,
                                                    const ushort* __restrict__ Xb,
                                                    const float* __restrict__ g,
                                                    const float* __restrict__ be,
                                                    ushort* __restrict__ T2b)
{
  int row = blockIdx.x;
  int tid = threadIdx.x;
  __shared__ float Ks[8 * 409];
  __shared__ float Vs[8 * 409];
  __shared__ float ps[4], ps2[4];
  {
    const uint4* K4 = (const uint4*)(Kg + (size_t)row * ND_);
    const uint4* V4 = (const uint4*)(Vg + (size_t)row * ND_);
    for (int i8 = tid; i8 < 384; i8 += 256) {
      int n = i8 >> 4, e8 = (i8 & 15) * 8;
      int h = e8 >> 4, f0 = e8 & 15;
      int basei = h * 409 + n * 17 + f0;
      union { uint4 u; ushort s[8]; } kv, vv;
      kv.u = K4[i8];
      vv.u = V4[i8];
      #pragma unroll
      for (int j = 0; j < 8; ++j) {
        Ks[basei + j] = bf2f(kv.s[j]);
        Vs[basei + j] = bf2f(vv.s[j]);
      }
    }
  }
  __syncthreads();
  float o[F_];
  float s = 0.f, s2 = 0.f;
  int n = tid >> 3, h = tid & 7;
  int cbase = n * D_ + h * F_;
  if (tid < 192) {
    float q[F_];
    {
      const ushort* qp = Qg + (size_t)row * ND_ + cbase;
      union { uint4 u[2]; ushort s[16]; } qv;
      qv.u[0] = *(const uint4*)qp;
      qv.u[1] = *(const uint4*)(qp + 8);
      #pragma unroll
      for (int f = 0; f < F_; ++f) q[f] = bf2f(qv.s[f]);
    }
    float sc[N_];
    float mx = -1e30f;
    const float* Kh = &Ks[h * 409];
    for (int m = 0; m < N_; ++m) {
      float sd = 0.f;
      #pragma unroll
      for (int f = 0; f < F_; ++f) sd += q[f] * Kh[m * 17 + f];
      sd *= 0.25f;
      sc[m] = sd;
      mx = fmaxf(mx, sd);
    }
    float den = 0.f;
    for (int m = 0; m < N_; ++m) { sc[m] = __expf(sc[m] - mx); den += sc[m]; }
    float inv = 1.f / den;
    #pragma unroll
    for (int f = 0; f < F_; ++f) o[f] = 0.f;
    const float* Vh = &Vs[h * 409];
    for (int m = 0; m < N_; ++m) {
      float p = sc[m] * inv;
      #pragma unroll
      for (int f = 0; f < F_; ++f) o[f] += p * Vh[m * 17 + f];
    }
    {
      const ushort* xp = Xb + (size_t)row * ND_ + cbase;
      union { uint4 u[2]; ushort s[16]; } xu;
      xu.u[0] = *(const uint4*)xp;
      xu.u[1] = *(const uint4*)(xp + 8);
      #pragma unroll
      for (int f = 0; f < F_; ++f) {
        float v = o[f] + bf2f(xu.s[f]);
        o[f] = v;
        s += v;
        s2 += v * v;
      }
    }
  }
  #pragma unroll
  for (int m = 1; m < 64; m <<= 1) {
    s += __shfl_xor(s, m, 64);
    s2 += __shfl_xor(s2, m, 64);
  }
  int w = tid >> 6;
  if ((tid & 63) == 0) { ps[w] = s; ps2[w] = s2; }
  __syncthreads();
  float ts = ps[0] + ps[1] + ps[2] + ps[3];
  float ts2 = ps2[0] + ps2[1] + ps2[2] + ps2[3];
  float mu = ts / (float)ND_;
  float var = ts2 / (float)ND_ - mu * mu;
  float rs = rsqrtf(var + 1e-5f);
  if (tid < 192) {
    union { uint4 u[2]; ushort s[16]; } ov;
    #pragma unroll
    for (int f = 0; f < F_; ++f)
      ov.s[f] = f2bf((o[f] - mu) * rs * g[cbase + f] + be[cbase + f]);
    ushort* op = T2b + (size_t)row * ND_ + cbase;
    *(uint4*)op = ov.u[0];
    *(uint4*)(op + 8) = ov.u[1];
  }
}

// ---------------- temporal attention via MFMA, transposed layout ------------------
__global__ __launch_bounds__(256) void k_temporal_mfma(const ushort* __restrict__ tQ,
                                                       const ushort* __restrict__ tK,
                                                       const ushort* __restrict__ tV,
                                                       ushort* __restrict__ Ob)
{
  long long gb = (long long)blockIdx.x * (T_ * F_);
  int tid = threadIdx.x;
  __shared__ ushort Kl[T_][20];
  __shared__ ushort Ql[T_][20];
  __shared__ ushort Vt[F_][200];
  {
    const uint4* Kg4 = (const uint4*)(tK + gb);
    const uint4* Qg4 = (const uint4*)(tQ + gb);
    const uint4* Vg4 = (const uint4*)(tV + gb);
    for (int task = tid; task < 1152; task += 256) {
      int ten = task / 384, idx = task - ten * 384;
      int t = idx >> 1, half = idx & 1;
      if (ten == 0) {
        uint4 v = Kg4[idx];
        *(uint2*)&Kl[t][half * 8] = make_uint2(v.x, v.y);
        *(uint2*)&Kl[t][half * 8 + 4] = make_uint2(v.z, v.w);
      } else if (ten == 1) {
        uint4 v = Qg4[idx];
        *(uint2*)&Ql[t][half * 8] = make_uint2(v.x, v.y);
        *(uint2*)&Ql[t][half * 8 + 4] = make_uint2(v.z, v.w);
      } else {
        union { uint4 u4; ushort s[8]; } vv;
        vv.u4 = Vg4[idx];
        #pragma unroll
        for (int f = 0; f < 8; ++f) Vt[half * 8 + f][t] = vv.s[f];
      }
    }
  }
  __syncthreads();
  int lane = tid & 63, wid = tid >> 6;
  int lr = lane & 15, lg = lane >> 4;
  const bf16x4_t z4 = (bf16x4_t){0, 0, 0, 0};
  const f32x4_t zf = (f32x4_t){0.f, 0.f, 0.f, 0.f};
  #pragma unroll
  for (int jj = 0; jj < 3; ++jj) {
    int q0 = (wid * 3 + jj) * 16;
    union { bf16x8_t v; bf16x4_t h4[2]; } qf;
    qf.h4[0] = *(const bf16x4_t*)&Ql[q0 + lr][lg * 4];
    qf.h4[1] = z4;
    f32x4_t d[12];
    #pragma unroll
    for (int i = 0; i < 12; ++i) {
      union { bf16x8_t v; bf16x4_t h4[2]; } kf;
      kf.h4[0] = *(const bf16x4_t*)&Kl[i * 16 + lr][lg * 4];
      kf.h4[1] = z4;
      d[i] = __builtin_amdgcn_mfma_f32_16x16x32_bf16(kf.v, qf.v, zf, 0, 0, 0);
    }
    int qg = q0 + lr;
    float lsum = 0.f;
    #pragma unroll
    for (int i = 0; i < 12; ++i) {
      #pragma unroll
      for (int r = 0; r < 4; ++r) {
        int k = i * 16 + lg * 4 + r;
        float p = __expf(d[i][r] * 0.25f + ((k < qg) ? 1.0f : 0.0f));
        d[i][r] = p;
        lsum += p;
      }
    }
    lsum += __shfl_xor(lsum, 16, 64);
    lsum += __shfl_xor(lsum, 32, 64);
    f32x4_t o = zf;
    #pragma unroll
    for (int i = 0; i < 6; ++i) {
      union { bf16x8_t v; bf16x4_t h4[2]; } vf;
      vf.h4[0] = *(const bf16x4_t*)&Vt[lr][i * 32 + lg * 4];
      vf.h4[1] = *(const bf16x4_t*)&Vt[lr][i * 32 + 16 + lg * 4];
      union { bf16x8_t v; uint uu[4]; } pf;
      pf.uu[0] = cvtpk(d[2 * i][0], d[2 * i][1]);
      pf.uu[1] = cvtpk(d[2 * i][2], d[2 * i][3]);
      pf.uu[2] = cvtpk(d[2 * i + 1][0], d[2 * i + 1][1]);
      pf.uu[3] = cvtpk(d[2 * i + 1][2], d[2 * i + 1][3]);
      o = __builtin_amdgcn_mfma_f32_16x16x32_bf16(vf.v, pf.v, o, 0, 0, 0);
    }
    float inv = 1.f / lsum;
    bf16x4_t ov;
    #pragma unroll
    for (int r = 0; r < 4; ++r) ov[r] = (short)f2bf(o[r] * inv);
    *(bf16x4_t*)(Ob + gb + (long long)qg * F_ + lg * 4) = ov;
  }
}

// ---------------- Ab = T2b + LN(Opjb + Xb)  (register-resident, no LDS buf) -------
__global__ __launch_bounds__(256) void k_lnres_add(const ushort* __restrict__ Ain,
                                                   const ushort* __restrict__ Xb,
                                                   const ushort* __restrict__ T2,
                                                   const float* __restrict__ g,
                                                   const float* __restrict__ be,
                                                   ushort* __restrict__ Ab)
{
  int row = blockIdx.x;
  int tid = threadIdx.x;
  __shared__ float ps[4], ps2[4];
  const uint4* Ar = (const uint4*)(Ain + (size_t)row * ND_);
  const uint4* Xr = (const uint4*)(Xb + (size_t)row * ND_);
  float v0[8], v1[8];
  float s = 0.f, s2 = 0.f;
  {
    uint4 av = Ar[tid], xv = Xr[tid];
    const ushort* ap = (const ushort*)&av;
    const ushort* xp = (const ushort*)&xv;
    #pragma unroll
    for (int j = 0; j < 8; ++j) {
      float v = bf2f(ap[j]) + bf2f(xp[j]);
      v0[j] = v;
      s += v;
      s2 += v * v;
    }
  }
  if (tid < 128) {
    uint4 av = Ar[tid + 256], xv = Xr[tid + 256];
    const ushort* ap = (const ushort*)&av;
    const ushort* xp = (const ushort*)&xv;
    #pragma unroll
    for (int j = 0; j < 8; ++j) {
      float v = bf2f(ap[j]) + bf2f(xp[j]);
      v1[j] = v;
      s += v;
      s2 += v * v;
    }
  }
  #pragma unroll
  for (int m = 1; m < 64; m <<= 1) {
    s += __shfl_xor(s, m, 64);
    s2 += __shfl_xor(s2, m, 64);
  }
  int w = tid >> 6;
  if ((tid & 63) == 0) { ps[w] = s; ps2[w] = s2; }
  __syncthreads();
  float ts = ps[0] + ps[1] + ps[2] + ps[3];
  float ts2 = ps2[0] + ps2[1] + ps2[2] + ps2[3];
  float mu = ts / (float)ND_;
  float var = ts2 / (float)ND_ - mu * mu;
  float rs = rsqrtf(var + 1e-5f);
  const uint4* Tr = (const uint4*)(T2 + (size_t)row * ND_);
  uint4* Or = (uint4*)(Ab + (size_t)row * ND_);
  {
    uint4 tv = Tr[tid];
    const ushort* tp = (const ushort*)&tv;
    uint4 ov;
    ushort* op = (ushort*)&ov;
    int i0 = tid * 8;
    #pragma unroll
    for (int j = 0; j < 8; ++j)
      op[j] = f2bf((v0[j] - mu) * rs * g[i0 + j] + be[i0 + j] + bf2f(tp[j]));
    Or[tid] = ov;
  }
  if (tid < 128) {
    uint4 tv = Tr[tid + 256];
    const ushort* tp = (const ushort*)&tv;
    uint4 ov;
    ushort* op = (ushort*)&ov;
    int i0 = (tid + 256) * 8;
    #pragma unroll
    for (int j = 0; j < 8; ++j)
      op[j] = f2bf((v1[j] - mu) * rs * g[i0 + j] + be[i0 + j] + bf2f(tp[j]));
    Or[tid + 256] = ov;
  }
}

// ---------------- final projection + input residual ----------------
__global__ __launch_bounds__(256) void k_final(const ushort* __restrict__ Xb,
                                               const float* __restrict__ Wf,
                                               const float* __restrict__ bf,
                                               const float* __restrict__ in,
                                               float* __restrict__ out)
{
  int row = blockIdx.x;   // t*B + b
  int t = row / B_, b = row % B_;
  int tid = threadIdx.x;
  __shared__ float xr[ND_];
  const uint4* Xr = (const uint4*)(Xb + (size_t)row * ND_);
  for (int i8 = tid; i8 < ND_ / 8; i8 += 256) {
    uint4 xv = Xr[i8];
    const ushort* xp = (const ushort*)&xv;
    #pragma unroll
    for (int j = 0; j < 8; ++j) xr[i8 * 8 + j] = bf2f(xp[j]);
  }
  __syncthreads();
  if (tid < N_ * M_) {
    int n = tid / M_, mm = tid % M_;
    float acc = bf[mm];
    for (int d = 0; d < D_; ++d) acc += xr[n * D_ + d] * Wf[(size_t)d * M_ + mm];
    size_t oi = ((size_t)b * T_ + t) * (N_ * M_) + tid;
    out[oi] = acc + in[oi];
  }
}

extern "C" void kernel_launch(void* const* d_in, const int* in_sizes, int n_in,
                              void* d_out, int out_size, void* d_ws, size_t ws_size,
                              hipStream_t stream)
{
  const float* inputs = (const float*)d_in[0];
  const float* emb_W  = (const float*)d_in[1];
  const float* emb_b  = (const float*)d_in[2];
  const float* sa_Wq  = (const float*)d_in[3];
  const float* sa_bq  = (const float*)d_in[4];
  const float* sa_Wk  = (const float*)d_in[5];
  const float* sa_bk  = (const float*)d_in[6];
  const float* sa_Wv  = (const float*)d_in[7];
  const float* sa_bv  = (const float*)d_in[8];
  const float* ta_Wq  = (const float*)d_in[9];
  const float* ta_bq  = (const float*)d_in[10];
  const float* ta_Wk  = (const float*)d_in[11];
  const float* ta_bk  = (const float*)d_in[12];
  const float* ta_Wv  = (const float*)d_in[13];
  const float* ta_bv  = (const float*)d_in[14];
  const float* ta_Wo  = (const float*)d_in[15];
  const float* ta_bo  = (const float*)d_in[16];
  const float* ln_g   = (const float*)d_in[17];
  const float* ln_b   = (const float*)d_in[18];
  const float* lns_g  = (const float*)d_in[19];
  const float* lns_b  = (const float*)d_in[20];
  const float* ff_W1  = (const float*)d_in[21];
  const float* ff_b1  = (const float*)d_in[22];
  const float* ff_W2  = (const float*)d_in[23];
  const float* ff_b2  = (const float*)d_in[24];
  const float* fin_W  = (const float*)d_in[25];
  const float* fin_b  = (const float*)d_in[26];
  float* out = (float*)d_out;

  // ---- workspace layout ----
  char* base = (char*)d_ws;
  ushort* Xb  = (ushort*)base;                       // [0, 2SZ)
  ushort* C0  = (ushort*)(base + 2 * SZ_);           // [2SZ, 14SZ): slots S0..S5
  ushort* T2b = (ushort*)(base + 14 * SZ_);          // [14SZ, 16SZ)
  ushort* sQ = C0;                       // S0
  ushort* sK = C0 + SZ_;                 // S1
  ushort* sV = C0 + 2 * SZ_;             // S2
  ushort* tQ = C0 + 3 * SZ_;             // S3 (transposed layout)
  ushort* tK = C0 + 4 * SZ_;             // S4 (transposed layout)
  ushort* tV = C0 + 5 * SZ_;             // S5 (transposed layout)
  ushort* AOb  = tV;                     // temporal attn writes S5 in place
  ushort* Opjb = sQ;                     // oproj out -> S0
  ushort* Ab   = sK;                     // lnres_add out -> S1
  ushort* hB   = tK;                     // FF hidden -> S4+S5

  ushort* wts = (ushort*)(base + 16 * SZ_);          // 2 layers x WL_
  float* fb   = (float*)(wts + 2 * WL_);             // 2 layers x 3328
  float* peT  = fb + 2 * 3328;                       // 589824

  // ---- both layers' weight packing (fragment layout), hoisted ----
  k_pack_sp<<<dim3(1677, 2), 256, 0, stream>>>(sa_Wq, sa_bq, sa_Wk, sa_bk,
                                               sa_Wv, sa_bv, wts, fb);
  PackWArgs pw;
  pw.src[0] = ta_Wq; pw.src[1] = ta_Wk; pw.src[2] = ta_Wv; pw.src[3] = ta_Wo;
  pw.src[4] = ff_W1; pw.src[5] = ff_W2;
  pw.wts = wts;
  k_pack_w<<<dim3(400, 2), 256, 0, stream>>>(pw);

  k_pe<<<(T_ * ND_ + 255) / 256, 256, 0, stream>>>(peT);
  k_embed<<<ROWS_, 256, 0, stream>>>(inputs, emb_W, emb_b, peT, Xb);

  for (int l = 0; l < 2; ++l) {
    ushort* wl = wts + (long long)l * WL_;
    ushort* sWq = wl;
    ushort* sWk = wl + 393216;
    ushort* sWv = wl + 409600;
    ushort* tWq = wl + 425984;
    ushort* tWk = wl + 819200;
    ushort* tWv = wl + 1212416;
    ushort* tWo = wl + 1605632;
    ushort* W1t = wl + 1998848;
    ushort* W2t = wl + 2031616;
    float* fl = fb + l * 3328;
    float* bqP = fl;
    float* bkP = fl + 3072;
    float* bvP = fl + 3200;

    Qkv6Args qa;
    qa.W[0] = sWk; qa.bias[0] = bkP;                         qa.C[0] = sK;
    qa.wGroup[0] = 0;     qa.biasGroup[0] = 0;   qa.tpose[0] = 0;
    qa.W[1] = sWv; qa.bias[1] = bvP;                         qa.C[1] = sV;
    qa.wGroup[1] = 0;     qa.biasGroup[1] = 0;   qa.tpose[1] = 0;
    qa.W[2] = sWq; qa.bias[2] = bqP;                         qa.C[2] = sQ;
    qa.wGroup[2] = 16384; qa.biasGroup[2] = 128; qa.tpose[2] = 0;
    qa.W[3] = tWq; qa.bias[3] = ta_bq + (size_t)l * N_ * D_; qa.C[3] = tQ;
    qa.wGroup[3] = 16384; qa.biasGroup[3] = 128; qa.tpose[3] = 1;
    qa.W[4] = tWk; qa.bias[4] = ta_bk + (size_t)l * N_ * D_; qa.C[4] = tK;
    qa.wGroup[4] = 16384; qa.biasGroup[4] = 128; qa.tpose[4] = 1;
    qa.W[5] = tWv; qa.bias[5] = ta_bv + (size_t)l * N_ * D_; qa.C[5] = tV;
    qa.wGroup[5] = 16384; qa.biasGroup[5] = 128; qa.tpose[5] = 1;
    k_qkv6<<<dim3(ROWS_ / 128, 6, N_), 256, 0, stream>>>(Xb, qa);

    k_spatial_ln<<<ROWS_, 256, 0, stream>>>(sQ, sK, sV, Xb, ln_g + (size_t)l * ND_,
                                            ln_b + (size_t)l * ND_, T2b);

    k_temporal_mfma<<<B_ * N_ * H_, 256, 0, stream>>>(tQ, tK, tV, AOb);
    k_oproj<<<dim3(ROWS_ / 64, 1, N_), 256, 0, stream>>>(
        AOb, tWo, ta_bo + (size_t)l * N_ * D_, Opjb);

    k_lnres_add<<<ROWS_, 256, 0, stream>>>(Opjb, Xb, T2b, ln_g + (size_t)l * ND_,
                                           ln_b + (size_t)l * ND_, Ab);

    k_ff1<<<dim3(ROWS_ * N_ / 64, 2, 1), 256, 0, stream>>>(
        Ab, W1t, ff_b1 + (size_t)l * FF_, hB);
    k_ff2_ln<<<dim3(ROWS_ * N_ / 64, 1, 1), 256, 0, stream>>>(
        hB, W2t, ff_b2 + (size_t)l * D_, Ab,
        lns_g + (size_t)l * D_, lns_b + (size_t)l * D_, Xb);
  }

  k_final<<<ROWS_, 256, 0, stream>>>(Xb, fin_W, fin_b, inputs, out);
}

// Round 25
// 418.973 us; speedup vs baseline: 1.1746x; 1.0177x over previous
//
#include <hip/hip_runtime.h>
#include <cmath>

namespace {
constexpr int B_ = 16, T_ = 192, N_ = 24, D_ = 128, M_ = 9, H_ = 8, F_ = 16, FF_ = 256;
constexpr int ND_ = N_ * D_;                       // 3072
constexpr int ROWS_ = T_ * B_;                     // 3072
constexpr long long SZ_ = (long long)ROWS_ * ND_;  // 9437184 elements
constexpr long long WL_ = 2064384;                 // ushorts per layer weight area
}

typedef __attribute__((ext_vector_type(8))) short bf16x8_t;
typedef __attribute__((ext_vector_type(4))) short bf16x4_t;
typedef __attribute__((ext_vector_type(4))) float f32x4_t;

static __device__ __forceinline__ ushort f2bf(float f) {
  union { float f; uint u; } v; v.f = f;
  uint r = v.u + 0x7fffu + ((v.u >> 16) & 1u);   // RNE
  return (ushort)(r >> 16);
}
static __device__ __forceinline__ float bf2f(ushort u) {
  union { uint u; float f; } v; v.u = ((uint)u) << 16; return v.f;
}
static __device__ __forceinline__ uint cvtpk(float lo, float hi) {
  uint r;
  asm("v_cvt_pk_bf16_f32 %0, %1, %2" : "=v"(r) : "v"(lo), "v"(hi));
  return r;
}
// fragment-major index, SIGMA slot permutation: slot(lg,rem) holds k = kq*32+lg*8+rem
static __device__ __forceinline__ int fragIdx(int e, int k, int KQ) {
  int n = e >> 4, lr = e & 15;
  int kq = k >> 5, kr = k & 31;
  int lg = kr >> 3, rem = kr & 7;
  return (((n * KQ + kq) * 64 + lg * 16 + lr) << 3) + rem;
}

// ---------------- positional-encoding table: pe[t][c], 192x3072 ----------------
__global__ __launch_bounds__(256) void k_pe(float* __restrict__ pe)
{
  int i = blockIdx.x * 256 + threadIdx.x;
  if (i >= T_ * ND_) return;
  int t = i / ND_, c = i % ND_;
  float freq = expf((float)(2 * (c >> 1)) * (-9.210340371976184f / 3072.0f));
  float ang = (float)t * freq;
  pe[i] = (c & 1) ? cosf(ang) : sinf(ang);
}

// ---------------- embedding + PE -> bf16 X ----------------
__global__ __launch_bounds__(256) void k_embed(const float* __restrict__ in,
                                               const float* __restrict__ Wemb,
                                               const float* __restrict__ bemb,
                                               const float* __restrict__ pe,
                                               ushort* __restrict__ Xb)
{
  int row = blockIdx.x;            // t*B + b
  int t = row / B_, b = row % B_;
  int tid = threadIdx.x;
  __shared__ float inr[N_ * M_];
  const float* ip = in + ((size_t)b * T_ + t) * (N_ * M_);
  if (tid < N_ * M_) inr[tid] = ip[tid];
  __syncthreads();
  uint* Xr = (uint*)(Xb + (size_t)row * ND_);
  const float* per = pe + (size_t)t * ND_;
  for (int cc = tid; cc < ND_ / 2; cc += 256) {
    int c = cc * 2;
    int n = c >> 7;
    int d = c & 127;
    const float* xr = &inr[n * M_];
    float a0 = bemb[n * D_ + d] + per[c];
    float a1 = bemb[n * D_ + d + 1] + per[c + 1];
    const float* wp = Wemb + (size_t)(n * M_) * D_ + d;
    #pragma unroll
    for (int m = 0; m < M_; ++m) {
      float xm = xr[m];
      a0 += xm * wp[(size_t)m * D_];
      a1 += xm * wp[(size_t)m * D_ + 1];
    }
    Xr[cc] = (uint)f2bf(a0) | ((uint)f2bf(a1) << 16);
  }
}

// ---------------- spatial weight/bias packing, FRAGMENT layout (sigma) ----------
__global__ __launch_bounds__(256) void k_pack_sp(const float* __restrict__ saWq,
                                                 const float* __restrict__ sabq,
                                                 const float* __restrict__ saWk,
                                                 const float* __restrict__ sabk,
                                                 const float* __restrict__ saWv,
                                                 const float* __restrict__ sabv,
                                                 ushort* __restrict__ wts,
                                                 float* __restrict__ fb)
{
  int l = blockIdx.y;
  int i = blockIdx.x * 256 + threadIdx.x;
  ushort* wl = wts + (long long)l * WL_;
  float* fl = fb + l * 3328;
  if (i < 393216) {                       // sWq frag: per joint gz, tile 128x128
    int gz = i >> 14, il = i & 16383;
    int j = il & 7;
    int lane = (il >> 3) & 63;
    int nk = il >> 9;                     // n*4+kq
    int kq = nk & 3, n8 = nk >> 2;
    int lr = lane & 15, lg = lane >> 4;
    int e = n8 * 16 + lr;
    int d = kq * 32 + lg * 8 + j;
    int h = e >> 4, f = e & 15;
    wl[i] = f2bf(saWq[(long long)l * 393216 + (((size_t)h * N_ + gz) * D_ + d) * F_ + f]);
  } else if (i < 409600) {                // sWk frag: tile 128x128
    int il = i - 393216;
    int j = il & 7;
    int lane = (il >> 3) & 63;
    int nk = il >> 9;
    int kq = nk & 3, n8 = nk >> 2;
    int lr = lane & 15, lg = lane >> 4;
    int e = n8 * 16 + lr;
    int d = kq * 32 + lg * 8 + j;
    int h = e >> 4, f = e & 15;
    wl[i] = f2bf(saWk[(long long)l * 16384 + ((size_t)h * D_ + d) * F_ + f]);
  } else if (i < 425984) {                // sWv frag
    int il = i - 409600;
    int j = il & 7;
    int lane = (il >> 3) & 63;
    int nk = il >> 9;
    int kq = nk & 3, n8 = nk >> 2;
    int lr = lane & 15, lg = lane >> 4;
    int e = n8 * 16 + lr;
    int d = kq * 32 + lg * 8 + j;
    int h = e >> 4, f = e & 15;
    wl[i] = f2bf(saWv[(long long)l * 16384 + ((size_t)h * D_ + d) * F_ + f]);
  } else if (i < 429056) {                // bqP[n][e]
    int j = i - 425984;
    int n = j >> 7, e = j & 127, h = e >> 4, f = e & 15;
    fl[j] = sabq[l * 3072 + ((size_t)h * N_ + n) * F_ + f];
  } else if (i < 429184) {
    int j = i - 429056, h = j >> 4, f = j & 15;
    fl[3072 + j] = sabk[l * 128 + h * F_ + f];
  } else if (i < 429312) {
    int j = i - 429184, h = j >> 4, f = j & 15;
    fl[3200 + j] = sabv[l * 128 + h * F_ + f];
  }
}

// ---------------- transposed weight packing -> FRAGMENT layout -------------------
struct PackWArgs {
  const float* src[6];     // layer-0 bases: taWq, taWk, taWv, taWo, ffW1, ffW2
  ushort* wts;
};
__global__ __launch_bounds__(256) void k_pack_w(PackWArgs args)
{
  __shared__ float tile[64][65];
  int l = blockIdx.y;
  int x = blockIdx.x;
  ushort* wl = args.wts + (long long)l * WL_;
  const float* sp; ushort* dp;
  int bx, by, Rr, Cc, mode;
  if (x < 384) {
    int ten = x / 96, rem = x % 96, g = rem / 4, tl = rem % 4;
    bx = tl & 1; by = tl >> 1; Rr = 128; Cc = 128; mode = 0;
    sp = args.src[ten] + (long long)l * 393216 + (long long)g * 16384;
    dp = wl + 425984 + (long long)ten * 393216 + (long long)g * 16384;
  } else if (x < 392) {
    int idx = x - 384; bx = idx & 3; by = idx >> 2; Rr = 128; Cc = 256; mode = 1;
    sp = args.src[4] + (long long)l * 32768;
    dp = wl + 1998848;
  } else {
    int idx = x - 392; bx = idx & 1; by = idx >> 1; Rr = 256; Cc = 128; mode = 2;
    sp = args.src[5] + (long long)l * 32768;
    dp = wl + 2031616;
  }
  int c0 = bx * 64, r0 = by * 64;
  int ci = threadIdx.x & 63, rq = threadIdx.x >> 6;
  #pragma unroll
  for (int k = 0; k < 16; ++k) {
    int r = rq * 16 + k;
    tile[r][ci] = sp[(long long)(r0 + r) * Cc + c0 + ci];
  }
  __syncthreads();
  int ri = threadIdx.x & 63, cq = threadIdx.x >> 6;
  #pragma unroll
  for (int k = 0; k < 16; ++k) {
    int c = cq * 16 + k;
    int eg = c0 + c;          // output-col (e) dim
    int kg = r0 + ri;         // k dim
    int idx;
    if (mode == 1)      idx = (eg >> 7) * 16384 + fragIdx(eg & 127, kg, 4);
    else if (mode == 2) idx = fragIdx(eg, kg, 8);
    else                idx = fragIdx(eg, kg, 4);
    dp[idx] = f2bf(tile[ri][c]);
  }
}

// ---------------- unified 6-projection MFMA GEMM (2 row-tiles/block) ------------
struct Qkv6Args {
  const ushort* W[6];
  const float* bias[6];
  ushort* C[6];
  long long wGroup[6];
  int biasGroup[6];
  int tpose[6];
};
__global__ __launch_bounds__(256) void k_qkv6(const ushort* __restrict__ A, Qkv6Args args)
{
  __shared__ ushort Wl[16384];          // 32 KB, flat fragment layout
  int p = blockIdx.y;
  int gz = blockIdx.z;
  int tid = threadIdx.x;
  int lane = tid & 63, wid = tid >> 6;
  int lr = lane & 15, lg = lane >> 4;
  {
    const ushort* Wf = args.W[p] + (long long)gz * args.wGroup[p];
    #pragma unroll
    for (int it = 0; it < 8; ++it) {
      int idx = (it * 256 + tid) << 3;
      *(uint4*)&Wl[idx] = *(const uint4*)(Wf + idx);
    }
  }
  __syncthreads();
  const float* bb = args.bias[p] + (long long)gz * args.biasGroup[p];
  #pragma unroll
  for (int tt = 0; tt < 2; ++tt) {
    int row0 = (blockIdx.x * 2 + tt) * 64 + wid * 16;
    bf16x8_t au[4];
    {
      const ushort* ap = A + (long long)gz * 128 + (long long)(row0 + lr) * ND_ + lg * 8;
      #pragma unroll
      for (int kq = 0; kq < 4; ++kq)
        au[kq] = *(const bf16x8_t*)(ap + kq * 32);
    }
    f32x4_t acc[8];
    #pragma unroll
    for (int n = 0; n < 8; ++n) acc[n] = (f32x4_t){0.f, 0.f, 0.f, 0.f};
    #pragma unroll
    for (int n = 0; n < 8; ++n) {
      #pragma unroll
      for (int kq = 0; kq < 4; ++kq) {
        bf16x8_t bu = *(const bf16x8_t*)&Wl[((n * 4 + kq) * 64 + lane) << 3];
        acc[n] = __builtin_amdgcn_mfma_f32_16x16x32_bf16(au[kq], bu, acc[n], 0, 0, 0);
      }
    }
    if (args.tpose[p]) {
      ushort* Cp = args.C[p];
      #pragma unroll
      for (int n = 0; n < 8; ++n) {
        float bv = bb[n * 16 + lr];
        #pragma unroll
        for (int r = 0; r < 4; ++r) {
          int rg = row0 + lg * 4 + r;
          int ttg = rg >> 4, bI = rg & 15;
          long long gI = ((long long)bI * N_ + gz) * H_ + n;
          Cp[(gI * T_ + ttg) * F_ + lr] = f2bf(acc[n][r] + bv);
        }
      }
    } else {
      ushort* Cp = args.C[p] + (long long)gz * 128;
      #pragma unroll
      for (int n = 0; n < 8; ++n) {
        float bv = bb[n * 16 + lr];
        #pragma unroll
        for (int r = 0; r < 4; ++r)
          Cp[(long long)(row0 + lg * 4 + r) * ND_ + n * 16 + lr] = f2bf(acc[n][r] + bv);
      }
    }
  }
}

// ---------------- FF1 (flat-LDS frag staging), relu -> bf16 out ----------------
__global__ __launch_bounds__(256) void k_ff1(
    const ushort* __restrict__ A, const ushort* __restrict__ Wt,
    const float* __restrict__ bias, ushort* __restrict__ Cout)
{
  __shared__ ushort Wl[16384];
  int tid = threadIdx.x;
  int lane = tid & 63, wid = tid >> 6;
  int lr = lane & 15, lg = lane >> 4;
  int row0 = blockIdx.x * 64 + wid * 16;
  {
    const ushort* Wf = Wt + (long long)blockIdx.y * 16384;
    #pragma unroll
    for (int it = 0; it < 8; ++it) {
      int idx = (it * 256 + tid) << 3;
      *(uint4*)&Wl[idx] = *(const uint4*)(Wf + idx);
    }
  }
  bf16x8_t au[4];
  {
    const ushort* ap = A + (long long)(row0 + lr) * 128 + lg * 8;
    #pragma unroll
    for (int kq = 0; kq < 4; ++kq)
      au[kq] = *(const bf16x8_t*)(ap + kq * 32);
  }
  __syncthreads();
  f32x4_t acc[8];
  #pragma unroll
  for (int n = 0; n < 8; ++n) acc[n] = (f32x4_t){0.f, 0.f, 0.f, 0.f};
  #pragma unroll
  for (int n = 0; n < 8; ++n) {
    #pragma unroll
    for (int kq = 0; kq < 4; ++kq) {
      bf16x8_t bu = *(const bf16x8_t*)&Wl[((n * 4 + kq) * 64 + lane) << 3];
      acc[n] = __builtin_amdgcn_mfma_f32_16x16x32_bf16(au[kq], bu, acc[n], 0, 0, 0);
    }
  }
  const float* bb = bias + blockIdx.y * 128;
  int ccolBase = blockIdx.y * 128 + lr;
  #pragma unroll
  for (int n = 0; n < 8; ++n) {
    float bv = bb[n * 16 + lr];
    #pragma unroll
    for (int r = 0; r < 4; ++r) {
      float v = fmaxf(acc[n][r] + bv, 0.f);
      Cout[(long long)(row0 + lg * 4 + r) * 256 + ccolBase + n * 16] = f2bf(v);
    }
  }
}

// ---------------- FF2 + residual + per-joint LN_128 fused -> Xb ----------------
__global__ __launch_bounds__(256) void k_ff2_ln(
    const ushort* __restrict__ A,      // hB: 73728 x 256
    const ushort* __restrict__ Wt,     // W2 frag layout (KQ=8)
    const float* __restrict__ bias,    // ff_b2 (128)
    const ushort* __restrict__ Res,    // Ab flat 73728 x 128
    const float* __restrict__ g,       // lns_g (128)
    const float* __restrict__ be,      // lns_b (128)
    ushort* __restrict__ Xb)           // flat 73728 x 128
{
  __shared__ ushort Wl[32768];          // 64 KB, flat fragment layout
  int tid = threadIdx.x;
  int lane = tid & 63, wid = tid >> 6;
  int lr = lane & 15, lg = lane >> 4;
  int row0 = blockIdx.x * 64 + wid * 16;
  {
    #pragma unroll
    for (int it = 0; it < 16; ++it) {
      int idx = (it * 256 + tid) << 3;
      *(uint4*)&Wl[idx] = *(const uint4*)(Wt + idx);
    }
  }
  bf16x8_t au[8];
  {
    const ushort* ap = A + (long long)(row0 + lr) * 256 + lg * 8;
    #pragma unroll
    for (int kq = 0; kq < 8; ++kq)
      au[kq] = *(const bf16x8_t*)(ap + kq * 32);
  }
  __syncthreads();
  f32x4_t acc[8];
  #pragma unroll
  for (int n = 0; n < 8; ++n) acc[n] = (f32x4_t){0.f, 0.f, 0.f, 0.f};
  #pragma unroll
  for (int n = 0; n < 8; ++n) {
    #pragma unroll
    for (int kq = 0; kq < 8; ++kq) {
      bf16x8_t bu = *(const bf16x8_t*)&Wl[((n * 8 + kq) * 64 + lane) << 3];
      acc[n] = __builtin_amdgcn_mfma_f32_16x16x32_bf16(au[kq], bu, acc[n], 0, 0, 0);
    }
  }
  // epilogue: + bias + residual, per-row LN over 128
  float s[4] = {0.f, 0.f, 0.f, 0.f};
  float s2[4] = {0.f, 0.f, 0.f, 0.f};
  #pragma unroll
  for (int n = 0; n < 8; ++n) {
    float bv = bias[n * 16 + lr];
    #pragma unroll
    for (int r = 0; r < 4; ++r) {
      float v = acc[n][r] + bv
              + bf2f(Res[(long long)(row0 + lg * 4 + r) * 128 + n * 16 + lr]);
      acc[n][r] = v;
      s[r] += v;
      s2[r] += v * v;
    }
  }
  #pragma unroll
  for (int m = 1; m < 16; m <<= 1) {
    #pragma unroll
    for (int r = 0; r < 4; ++r) {
      s[r] += __shfl_xor(s[r], m, 64);
      s2[r] += __shfl_xor(s2[r], m, 64);
    }
  }
  #pragma unroll
  for (int r = 0; r < 4; ++r) {
    float mu = s[r] * (1.f / 128.f);
    float var = s2[r] * (1.f / 128.f) - mu * mu;
    float rs = rsqrtf(var + 1e-5f);
    long long rb = (long long)(row0 + lg * 4 + r) * 128;
    #pragma unroll
    for (int n = 0; n < 8; ++n) {
      int col = n * 16 + lr;
      Xb[rb + col] = f2bf((acc[n][r] - mu) * rs * g[col] + be[col]);
    }
  }
}

// ---------------- oproj (flat-LDS frag staging); A transposed TT layout ----------
__global__ __launch_bounds__(256) void k_oproj(const ushort* __restrict__ A,
                                               const ushort* __restrict__ Wt,
                                               const float* __restrict__ bias,
                                               ushort* __restrict__ Cout)
{
  __shared__ ushort Wl[16384];
  int gz = blockIdx.z;
  int tid = threadIdx.x;
  int lane = tid & 63, wid = tid >> 6;
  int lr = lane & 15, lg = lane >> 4;
  int row0 = blockIdx.x * 64 + wid * 16;   // multiple of 16 -> t uniform, b = lr
  int tW = row0 >> 4;
  {
    const ushort* Wf = Wt + (long long)gz * 16384;
    #pragma unroll
    for (int it = 0; it < 8; ++it) {
      int idx = (it * 256 + tid) << 3;
      *(uint4*)&Wl[idx] = *(const uint4*)(Wf + idx);
    }
  }
  union { bf16x8_t v; bf16x4_t h[2]; } au[4];
  {
    // sigma layout: slot(lg, hi*4+j) holds k = kq*32 + lg*8 + hi*4 + j
    // k -> h = 2*kq + (lg>>1), f = (lg&1)*8 + hi*4 + j
    const ushort* ab = A + (((long long)lr * N_ + gz) * H_ + (lg >> 1)) * ((long long)T_ * F_)
                         + (long long)tW * F_ + (lg & 1) * 8;
    #pragma unroll
    for (int kq = 0; kq < 4; ++kq) {
      au[kq].h[0] = *(const bf16x4_t*)(ab + (long long)(2 * kq) * (T_ * F_));
      au[kq].h[1] = *(const bf16x4_t*)(ab + (long long)(2 * kq) * (T_ * F_) + 4);
    }
  }
  __syncthreads();
  f32x4_t acc[8];
  #pragma unroll
  for (int n = 0; n < 8; ++n) acc[n] = (f32x4_t){0.f, 0.f, 0.f, 0.f};
  #pragma unroll
  for (int n = 0; n < 8; ++n) {
    #pragma unroll
    for (int kq = 0; kq < 4; ++kq) {
      bf16x8_t bu = *(const bf16x8_t*)&Wl[((n * 4 + kq) * 64 + lane) << 3];
      acc[n] = __builtin_amdgcn_mfma_f32_16x16x32_bf16(au[kq].v, bu, acc[n], 0, 0, 0);
    }
  }
  const float* bb = bias + (long long)gz * 128;
  ushort* C = Cout + (long long)gz * 128;
  #pragma unroll
  for (int n = 0; n < 8; ++n) {
    float bv = bb[n * 16 + lr];
    #pragma unroll
    for (int r = 0; r < 4; ++r)
      C[(long long)(row0 + lg * 4 + r) * ND_ + n * 16 + lr] = f2bf(acc[n][r] + bv);
  }
}

// ---------------- fused spatial attention + LN -> T2b, register-resident O --------
__global__ __launch_bounds__(256) void k_spatial_ln(const ushort* __restrict__ Qg,
                                                    const ushort* __restrict__ Kg,
                                                    const ushort* __restrict__ Vg,
                                                    const ushort* __restrict__ Xb,
                                                    const float* __restrict__ g,
                                                    const float* __restrict__ be,
                                                    ushort* __restrict__ T2b)
{
  int row = blockIdx.x;
  int tid = threadIdx.x;
  __shared__ float Ks[8 * 409];
  __shared__ float Vs[8 * 409];
  __shared__ float ps[4], ps2[4];
  {
    const uint4* K4 = (const uint4*)(Kg + (size_t)row * ND_);
    const uint4* V4 = (const uint4*)(Vg + (size_t)row * ND_);
    for (int i8 = tid; i8 < 384; i8 += 256) {
      int n = i8 >> 4, e8 = (i8 & 15) * 8;
      int h = e8 >> 4, f0 = e8 & 15;
      int basei = h * 409 + n * 17 + f0;
      union { uint4 u; ushort s[8]; } kv, vv;
      kv.u = K4[i8];
      vv.u = V4[i8];
      #pragma unroll
      for (int j = 0; j < 8; ++j) {
        Ks[basei + j] = bf2f(kv.s[j]);
        Vs[basei + j] = bf2f(vv.s[j]);
      }
    }
  }
  __syncthreads();
  float o[F_];
  float s = 0.f, s2 = 0.f;
  int n = tid >> 3, h = tid & 7;
  int cbase = n * D_ + h * F_;
  if (tid < 192) {
    float q[F_];
    {
      const ushort* qp = Qg + (size_t)row * ND_ + cbase;
      union { uint4 u[2]; ushort s[16]; } qv;
      qv.u[0] = *(const uint4*)qp;
      qv.u[1] = *(const uint4*)(qp + 8);
      #pragma unroll
      for (int f = 0; f < F_; ++f) q[f] = bf2f(qv.s[f]);
    }
    float sc[N_];
    float mx = -1e30f;
    const float* Kh = &Ks[h * 409];
    for (int m = 0; m < N_; ++m) {
      float sd = 0.f;
      #pragma unroll
      for (int f = 0; f < F_; ++f) sd += q[f] * Kh[m * 17 + f];
      sd *= 0.25f;
      sc[m] = sd;
      mx = fmaxf(mx, sd);
    }
    float den = 0.f;
    for (int m = 0; m < N_; ++m) { sc[m] = __expf(sc[m] - mx); den += sc[m]; }
    float inv = 1.f / den;
    #pragma unroll
    for (int f = 0; f < F_; ++f) o[f] = 0.f;
    const float* Vh = &Vs[h * 409];
    for (int m = 0; m < N_; ++m) {
      float p = sc[m] * inv;
      #pragma unroll
      for (int f = 0; f < F_; ++f) o[f] += p * Vh[m * 17 + f];
    }
    {
      const ushort* xp = Xb + (size_t)row * ND_ + cbase;
      union { uint4 u[2]; ushort s[16]; } xu;
      xu.u[0] = *(const uint4*)xp;
      xu.u[1] = *(const uint4*)(xp + 8);
      #pragma unroll
      for (int f = 0; f < F_; ++f) {
        float v = o[f] + bf2f(xu.s[f]);
        o[f] = v;
        s += v;
        s2 += v * v;
      }
    }
  }
  #pragma unroll
  for (int m = 1; m < 64; m <<= 1) {
    s += __shfl_xor(s, m, 64);
    s2 += __shfl_xor(s2, m, 64);
  }
  int w = tid >> 6;
  if ((tid & 63) == 0) { ps[w] = s; ps2[w] = s2; }
  __syncthreads();
  float ts = ps[0] + ps[1] + ps[2] + ps[3];
  float ts2 = ps2[0] + ps2[1] + ps2[2] + ps2[3];
  float mu = ts / (float)ND_;
  float var = ts2 / (float)ND_ - mu * mu;
  float rs = rsqrtf(var + 1e-5f);
  if (tid < 192) {
    union { uint4 u[2]; ushort s[16]; } ov;
    #pragma unroll
    for (int f = 0; f < F_; ++f)
      ov.s[f] = f2bf((o[f] - mu) * rs * g[cbase + f] + be[cbase + f]);
    ushort* op = T2b + (size_t)row * ND_ + cbase;
    *(uint4*)op = ov.u[0];
    *(uint4*)(op + 8) = ov.u[1];
  }
}

// ---------------- temporal attention via MFMA, fused per-K-pair pipeline ----------
// per pair: QK^T mfma x2 -> exp+mask x8 -> cvtpk x4 -> PV mfma (low VGPR)
__global__ __launch_bounds__(256) void k_temporal_mfma(const ushort* __restrict__ tQ,
                                                       const ushort* __restrict__ tK,
                                                       const ushort* __restrict__ tV,
                                                       ushort* __restrict__ Ob)
{
  long long gb = (long long)blockIdx.x * (T_ * F_);
  int tid = threadIdx.x;
  __shared__ ushort Kl[T_][20];
  __shared__ ushort Ql[T_][20];
  __shared__ ushort Vt[F_][200];
  {
    const uint4* Kg4 = (const uint4*)(tK + gb);
    const uint4* Qg4 = (const uint4*)(tQ + gb);
    const uint4* Vg4 = (const uint4*)(tV + gb);
    for (int task = tid; task < 1152; task += 256) {
      int ten = task / 384, idx = task - ten * 384;
      int t = idx >> 1, half = idx & 1;
      if (ten == 0) {
        uint4 v = Kg4[idx];
        *(uint2*)&Kl[t][half * 8] = make_uint2(v.x, v.y);
        *(uint2*)&Kl[t][half * 8 + 4] = make_uint2(v.z, v.w);
      } else if (ten == 1) {
        uint4 v = Qg4[idx];
        *(uint2*)&Ql[t][half * 8] = make_uint2(v.x, v.y);
        *(uint2*)&Ql[t][half * 8 + 4] = make_uint2(v.z, v.w);
      } else {
        union { uint4 u4; ushort s[8]; } vv;
        vv.u4 = Vg4[idx];
        #pragma unroll
        for (int f = 0; f < 8; ++f) Vt[half * 8 + f][t] = vv.s[f];
      }
    }
  }
  __syncthreads();
  int lane = tid & 63, wid = tid >> 6;
  int lr = lane & 15, lg = lane >> 4;
  const bf16x4_t z4 = (bf16x4_t){0, 0, 0, 0};
  const f32x4_t zf = (f32x4_t){0.f, 0.f, 0.f, 0.f};
  #pragma unroll
  for (int jj = 0; jj < 3; ++jj) {
    int q0 = (wid * 3 + jj) * 16;
    union { bf16x8_t v; bf16x4_t h4[2]; } qf;
    qf.h4[0] = *(const bf16x4_t*)&Ql[q0 + lr][lg * 4];
    qf.h4[1] = z4;
    int qg = q0 + lr;
    float lsum = 0.f;
    f32x4_t o = zf;
    #pragma unroll
    for (int i = 0; i < 6; ++i) {
      union { bf16x8_t v; bf16x4_t h4[2]; } kf0, kf1;
      kf0.h4[0] = *(const bf16x4_t*)&Kl[(2 * i) * 16 + lr][lg * 4];
      kf0.h4[1] = z4;
      kf1.h4[0] = *(const bf16x4_t*)&Kl[(2 * i + 1) * 16 + lr][lg * 4];
      kf1.h4[1] = z4;
      f32x4_t d0 = __builtin_amdgcn_mfma_f32_16x16x32_bf16(kf0.v, qf.v, zf, 0, 0, 0);
      f32x4_t d1 = __builtin_amdgcn_mfma_f32_16x16x32_bf16(kf1.v, qf.v, zf, 0, 0, 0);
      #pragma unroll
      for (int r = 0; r < 4; ++r) {
        int k = (2 * i) * 16 + lg * 4 + r;
        float p = __expf(d0[r] * 0.25f + ((k < qg) ? 1.0f : 0.0f));
        d0[r] = p;
        lsum += p;
      }
      #pragma unroll
      for (int r = 0; r < 4; ++r) {
        int k = (2 * i + 1) * 16 + lg * 4 + r;
        float p = __expf(d1[r] * 0.25f + ((k < qg) ? 1.0f : 0.0f));
        d1[r] = p;
        lsum += p;
      }
      union { bf16x8_t v; bf16x4_t h4[2]; } vf;
      vf.h4[0] = *(const bf16x4_t*)&Vt[lr][i * 32 + lg * 4];
      vf.h4[1] = *(const bf16x4_t*)&Vt[lr][i * 32 + 16 + lg * 4];
      union { bf16x8_t v; uint uu[4]; } pf;
      pf.uu[0] = cvtpk(d0[0], d0[1]);
      pf.uu[1] = cvtpk(d0[2], d0[3]);
      pf.uu[2] = cvtpk(d1[0], d1[1]);
      pf.uu[3] = cvtpk(d1[2], d1[3]);
      o = __builtin_amdgcn_mfma_f32_16x16x32_bf16(vf.v, pf.v, o, 0, 0, 0);
    }
    lsum += __shfl_xor(lsum, 16, 64);
    lsum += __shfl_xor(lsum, 32, 64);
    float inv = 1.f / lsum;
    bf16x4_t ov;
    #pragma unroll
    for (int r = 0; r < 4; ++r) ov[r] = (short)f2bf(o[r] * inv);
    *(bf16x4_t*)(Ob + gb + (long long)qg * F_ + lg * 4) = ov;
  }
}

// ---------------- Ab = T2b + LN(Opjb + Xb)  (register-resident, no LDS buf) -------
__global__ __launch_bounds__(256) void k_lnres_add(const ushort* __restrict__ Ain,
                                                   const ushort* __restrict__ Xb,
                                                   const ushort* __restrict__ T2,
                                                   const float* __restrict__ g,
                                                   const float* __restrict__ be,
                                                   ushort* __restrict__ Ab)
{
  int row = blockIdx.x;
  int tid = threadIdx.x;
  __shared__ float ps[4], ps2[4];
  const uint4* Ar = (const uint4*)(Ain + (size_t)row * ND_);
  const uint4* Xr = (const uint4*)(Xb + (size_t)row * ND_);
  float v0[8], v1[8];
  float s = 0.f, s2 = 0.f;
  {
    uint4 av = Ar[tid], xv = Xr[tid];
    const ushort* ap = (const ushort*)&av;
    const ushort* xp = (const ushort*)&xv;
    #pragma unroll
    for (int j = 0; j < 8; ++j) {
      float v = bf2f(ap[j]) + bf2f(xp[j]);
      v0[j] = v;
      s += v;
      s2 += v * v;
    }
  }
  if (tid < 128) {
    uint4 av = Ar[tid + 256], xv = Xr[tid + 256];
    const ushort* ap = (const ushort*)&av;
    const ushort* xp = (const ushort*)&xv;
    #pragma unroll
    for (int j = 0; j < 8; ++j) {
      float v = bf2f(ap[j]) + bf2f(xp[j]);
      v1[j] = v;
      s += v;
      s2 += v * v;
    }
  }
  #pragma unroll
  for (int m = 1; m < 64; m <<= 1) {
    s += __shfl_xor(s, m, 64);
    s2 += __shfl_xor(s2, m, 64);
  }
  int w = tid >> 6;
  if ((tid & 63) == 0) { ps[w] = s; ps2[w] = s2; }
  __syncthreads();
  float ts = ps[0] + ps[1] + ps[2] + ps[3];
  float ts2 = ps2[0] + ps2[1] + ps2[2] + ps2[3];
  float mu = ts / (float)ND_;
  float var = ts2 / (float)ND_ - mu * mu;
  float rs = rsqrtf(var + 1e-5f);
  const uint4* Tr = (const uint4*)(T2 + (size_t)row * ND_);
  uint4* Or = (uint4*)(Ab + (size_t)row * ND_);
  {
    uint4 tv = Tr[tid];
    const ushort* tp = (const ushort*)&tv;
    uint4 ov;
    ushort* op = (ushort*)&ov;
    int i0 = tid * 8;
    #pragma unroll
    for (int j = 0; j < 8; ++j)
      op[j] = f2bf((v0[j] - mu) * rs * g[i0 + j] + be[i0 + j] + bf2f(tp[j]));
    Or[tid] = ov;
  }
  if (tid < 128) {
    uint4 tv = Tr[tid + 256];
    const ushort* tp = (const ushort*)&tv;
    uint4 ov;
    ushort* op = (ushort*)&ov;
    int i0 = (tid + 256) * 8;
    #pragma unroll
    for (int j = 0; j < 8; ++j)
      op[j] = f2bf((v1[j] - mu) * rs * g[i0 + j] + be[i0 + j] + bf2f(tp[j]));
    Or[tid + 256] = ov;
  }
}

// ---------------- final projection + input residual ----------------
__global__ __launch_bounds__(256) void k_final(const ushort* __restrict__ Xb,
                                               const float* __restrict__ Wf,
                                               const float* __restrict__ bf,
                                               const float* __restrict__ in,
                                               float* __restrict__ out)
{
  int row = blockIdx.x;   // t*B + b
  int t = row / B_, b = row % B_;
  int tid = threadIdx.x;
  __shared__ float xr[ND_];
  const uint4* Xr = (const uint4*)(Xb + (size_t)row * ND_);
  for (int i8 = tid; i8 < ND_ / 8; i8 += 256) {
    uint4 xv = Xr[i8];
    const ushort* xp = (const ushort*)&xv;
    #pragma unroll
    for (int j = 0; j < 8; ++j) xr[i8 * 8 + j] = bf2f(xp[j]);
  }
  __syncthreads();
  if (tid < N_ * M_) {
    int n = tid / M_, mm = tid % M_;
    float acc = bf[mm];
    for (int d = 0; d < D_; ++d) acc += xr[n * D_ + d] * Wf[(size_t)d * M_ + mm];
    size_t oi = ((size_t)b * T_ + t) * (N_ * M_) + tid;
    out[oi] = acc + in[oi];
  }
}

extern "C" void kernel_launch(void* const* d_in, const int* in_sizes, int n_in,
                              void* d_out, int out_size, void* d_ws, size_t ws_size,
                              hipStream_t stream)
{
  const float* inputs = (const float*)d_in[0];
  const float* emb_W  = (const float*)d_in[1];
  const float* emb_b  = (const float*)d_in[2];
  const float* sa_Wq  = (const float*)d_in[3];
  const float* sa_bq  = (const float*)d_in[4];
  const float* sa_Wk  = (const float*)d_in[5];
  const float* sa_bk  = (const float*)d_in[6];
  const float* sa_Wv  = (const float*)d_in[7];
  const float* sa_bv  = (const float*)d_in[8];
  const float* ta_Wq  = (const float*)d_in[9];
  const float* ta_bq  = (const float*)d_in[10];
  const float* ta_Wk  = (const float*)d_in[11];
  const float* ta_bk  = (const float*)d_in[12];
  const float* ta_Wv  = (const float*)d_in[13];
  const float* ta_bv  = (const float*)d_in[14];
  const float* ta_Wo  = (const float*)d_in[15];
  const float* ta_bo  = (const float*)d_in[16];
  const float* ln_g   = (const float*)d_in[17];
  const float* ln_b   = (const float*)d_in[18];
  const float* lns_g  = (const float*)d_in[19];
  const float* lns_b  = (const float*)d_in[20];
  const float* ff_W1  = (const float*)d_in[21];
  const float* ff_b1  = (const float*)d_in[22];
  const float* ff_W2  = (const float*)d_in[23];
  const float* ff_b2  = (const float*)d_in[24];
  const float* fin_W  = (const float*)d_in[25];
  const float* fin_b  = (const float*)d_in[26];
  float* out = (float*)d_out;

  // ---- workspace layout ----
  char* base = (char*)d_ws;
  ushort* Xb  = (ushort*)base;                       // [0, 2SZ)
  ushort* C0  = (ushort*)(base + 2 * SZ_);           // [2SZ, 14SZ): slots S0..S5
  ushort* T2b = (ushort*)(base + 14 * SZ_);          // [14SZ, 16SZ)
  ushort* sQ = C0;                       // S0
  ushort* sK = C0 + SZ_;                 // S1
  ushort* sV = C0 + 2 * SZ_;             // S2
  ushort* tQ = C0 + 3 * SZ_;             // S3 (transposed layout)
  ushort* tK = C0 + 4 * SZ_;             // S4 (transposed layout)
  ushort* tV = C0 + 5 * SZ_;             // S5 (transposed layout)
  ushort* AOb  = tV;                     // temporal attn writes S5 in place
  ushort* Opjb = sQ;                     // oproj out -> S0
  ushort* Ab   = sK;                     // lnres_add out -> S1
  ushort* hB   = tK;                     // FF hidden -> S4+S5

  ushort* wts = (ushort*)(base + 16 * SZ_);          // 2 layers x WL_
  float* fb   = (float*)(wts + 2 * WL_);             // 2 layers x 3328
  float* peT  = fb + 2 * 3328;                       // 589824

  // ---- both layers' weight packing (fragment layout), hoisted ----
  k_pack_sp<<<dim3(1677, 2), 256, 0, stream>>>(sa_Wq, sa_bq, sa_Wk, sa_bk,
                                               sa_Wv, sa_bv, wts, fb);
  PackWArgs pw;
  pw.src[0] = ta_Wq; pw.src[1] = ta_Wk; pw.src[2] = ta_Wv; pw.src[3] = ta_Wo;
  pw.src[4] = ff_W1; pw.src[5] = ff_W2;
  pw.wts = wts;
  k_pack_w<<<dim3(400, 2), 256, 0, stream>>>(pw);

  k_pe<<<(T_ * ND_ + 255) / 256, 256, 0, stream>>>(peT);
  k_embed<<<ROWS_, 256, 0, stream>>>(inputs, emb_W, emb_b, peT, Xb);

  for (int l = 0; l < 2; ++l) {
    ushort* wl = wts + (long long)l * WL_;
    ushort* sWq = wl;
    ushort* sWk = wl + 393216;
    ushort* sWv = wl + 409600;
    ushort* tWq = wl + 425984;
    ushort* tWk = wl + 819200;
    ushort* tWv = wl + 1212416;
    ushort* tWo = wl + 1605632;
    ushort* W1t = wl + 1998848;
    ushort* W2t = wl + 2031616;
    float* fl = fb + l * 3328;
    float* bqP = fl;
    float* bkP = fl + 3072;
    float* bvP = fl + 3200;

    Qkv6Args qa;
    qa.W[0] = sWk; qa.bias[0] = bkP;                         qa.C[0] = sK;
    qa.wGroup[0] = 0;     qa.biasGroup[0] = 0;   qa.tpose[0] = 0;
    qa.W[1] = sWv; qa.bias[1] = bvP;                         qa.C[1] = sV;
    qa.wGroup[1] = 0;     qa.biasGroup[1] = 0;   qa.tpose[1] = 0;
    qa.W[2] = sWq; qa.bias[2] = bqP;                         qa.C[2] = sQ;
    qa.wGroup[2] = 16384; qa.biasGroup[2] = 128; qa.tpose[2] = 0;
    qa.W[3] = tWq; qa.bias[3] = ta_bq + (size_t)l * N_ * D_; qa.C[3] = tQ;
    qa.wGroup[3] = 16384; qa.biasGroup[3] = 128; qa.tpose[3] = 1;
    qa.W[4] = tWk; qa.bias[4] = ta_bk + (size_t)l * N_ * D_; qa.C[4] = tK;
    qa.wGroup[4] = 16384; qa.biasGroup[4] = 128; qa.tpose[4] = 1;
    qa.W[5] = tWv; qa.bias[5] = ta_bv + (size_t)l * N_ * D_; qa.C[5] = tV;
    qa.wGroup[5] = 16384; qa.biasGroup[5] = 128; qa.tpose[5] = 1;
    k_qkv6<<<dim3(ROWS_ / 128, 6, N_), 256, 0, stream>>>(Xb, qa);

    k_spatial_ln<<<ROWS_, 256, 0, stream>>>(sQ, sK, sV, Xb, ln_g + (size_t)l * ND_,
                                            ln_b + (size_t)l * ND_, T2b);

    k_temporal_mfma<<<B_ * N_ * H_, 256, 0, stream>>>(tQ, tK, tV, AOb);
    k_oproj<<<dim3(ROWS_ / 64, 1, N_), 256, 0, stream>>>(
        AOb, tWo, ta_bo + (size_t)l * N_ * D_, Opjb);

    k_lnres_add<<<ROWS_, 256, 0, stream>>>(Opjb, Xb, T2b, ln_g + (size_t)l * ND_,
                                           ln_b + (size_t)l * ND_, Ab);

    k_ff1<<<dim3(ROWS_ * N_ / 64, 2, 1), 256, 0, stream>>>(
        Ab, W1t, ff_b1 + (size_t)l * FF_, hB);
    k_ff2_ln<<<dim3(ROWS_ * N_ / 64, 1, 1), 256, 0, stream>>>(
        hB, W2t, ff_b2 + (size_t)l * D_, Ab,
        lns_g + (size_t)l * D_, lns_b + (size_t)l * D_, Xb);
  }

  k_final<<<ROWS_, 256, 0, stream>>>(Xb, fin_W, fin_b, inputs, out);
}

// Round 26
// 416.694 us; speedup vs baseline: 1.1810x; 1.0055x over previous
//
#include <hip/hip_runtime.h>
#include <cmath>

namespace {
constexpr int B_ = 16, T_ = 192, N_ = 24, D_ = 128, M_ = 9, H_ = 8, F_ = 16, FF_ = 256;
constexpr int ND_ = N_ * D_;                       // 3072
constexpr int ROWS_ = T_ * B_;                     // 3072
constexpr long long SZ_ = (long long)ROWS_ * ND_;  // 9437184 elements
constexpr long long WL_ = 2064384;                 // ushorts per layer weight area
}

typedef __attribute__((ext_vector_type(8))) short bf16x8_t;
typedef __attribute__((ext_vector_type(4))) short bf16x4_t;
typedef __attribute__((ext_vector_type(4))) float f32x4_t;

static __device__ __forceinline__ ushort f2bf(float f) {
  union { float f; uint u; } v; v.f = f;
  uint r = v.u + 0x7fffu + ((v.u >> 16) & 1u);   // RNE
  return (ushort)(r >> 16);
}
static __device__ __forceinline__ float bf2f(ushort u) {
  union { uint u; float f; } v; v.u = ((uint)u) << 16; return v.f;
}
static __device__ __forceinline__ uint cvtpk(float lo, float hi) {
  uint r;
  asm("v_cvt_pk_bf16_f32 %0, %1, %2" : "=v"(r) : "v"(lo), "v"(hi));
  return r;
}
// fragment-major index, SIGMA slot permutation: slot(lg,rem) holds k = kq*32+lg*8+rem
static __device__ __forceinline__ int fragIdx(int e, int k, int KQ) {
  int n = e >> 4, lr = e & 15;
  int kq = k >> 5, kr = k & 31;
  int lg = kr >> 3, rem = kr & 7;
  return (((n * KQ + kq) * 64 + lg * 16 + lr) << 3) + rem;
}

// ---------------- positional-encoding table: pe[t][c], 192x3072 ----------------
__global__ __launch_bounds__(256) void k_pe(float* __restrict__ pe)
{
  int i = blockIdx.x * 256 + threadIdx.x;
  if (i >= T_ * ND_) return;
  int t = i / ND_, c = i % ND_;
  float freq = expf((float)(2 * (c >> 1)) * (-9.210340371976184f / 3072.0f));
  float ang = (float)t * freq;
  pe[i] = (c & 1) ? cosf(ang) : sinf(ang);
}

// ---------------- embedding + PE -> bf16 X ----------------
__global__ __launch_bounds__(256) void k_embed(const float* __restrict__ in,
                                               const float* __restrict__ Wemb,
                                               const float* __restrict__ bemb,
                                               const float* __restrict__ pe,
                                               ushort* __restrict__ Xb)
{
  int row = blockIdx.x;            // t*B + b
  int t = row / B_, b = row % B_;
  int tid = threadIdx.x;
  __shared__ float inr[N_ * M_];
  const float* ip = in + ((size_t)b * T_ + t) * (N_ * M_);
  if (tid < N_ * M_) inr[tid] = ip[tid];
  __syncthreads();
  uint* Xr = (uint*)(Xb + (size_t)row * ND_);
  const float* per = pe + (size_t)t * ND_;
  for (int cc = tid; cc < ND_ / 2; cc += 256) {
    int c = cc * 2;
    int n = c >> 7;
    int d = c & 127;
    const float* xr = &inr[n * M_];
    float a0 = bemb[n * D_ + d] + per[c];
    float a1 = bemb[n * D_ + d + 1] + per[c + 1];
    const float* wp = Wemb + (size_t)(n * M_) * D_ + d;
    #pragma unroll
    for (int m = 0; m < M_; ++m) {
      float xm = xr[m];
      a0 += xm * wp[(size_t)m * D_];
      a1 += xm * wp[(size_t)m * D_ + 1];
    }
    Xr[cc] = (uint)f2bf(a0) | ((uint)f2bf(a1) << 16);
  }
}

// ---------------- spatial weight/bias packing, FRAGMENT layout (sigma) ----------
__global__ __launch_bounds__(256) void k_pack_sp(const float* __restrict__ saWq,
                                                 const float* __restrict__ sabq,
                                                 const float* __restrict__ saWk,
                                                 const float* __restrict__ sabk,
                                                 const float* __restrict__ saWv,
                                                 const float* __restrict__ sabv,
                                                 ushort* __restrict__ wts,
                                                 float* __restrict__ fb)
{
  int l = blockIdx.y;
  int i = blockIdx.x * 256 + threadIdx.x;
  ushort* wl = wts + (long long)l * WL_;
  float* fl = fb + l * 3328;
  if (i < 393216) {                       // sWq frag: per joint gz, tile 128x128
    int gz = i >> 14, il = i & 16383;
    int j = il & 7;
    int lane = (il >> 3) & 63;
    int nk = il >> 9;                     // n*4+kq
    int kq = nk & 3, n8 = nk >> 2;
    int lr = lane & 15, lg = lane >> 4;
    int e = n8 * 16 + lr;
    int d = kq * 32 + lg * 8 + j;
    int h = e >> 4, f = e & 15;
    wl[i] = f2bf(saWq[(long long)l * 393216 + (((size_t)h * N_ + gz) * D_ + d) * F_ + f]);
  } else if (i < 409600) {                // sWk frag: tile 128x128
    int il = i - 393216;
    int j = il & 7;
    int lane = (il >> 3) & 63;
    int nk = il >> 9;
    int kq = nk & 3, n8 = nk >> 2;
    int lr = lane & 15, lg = lane >> 4;
    int e = n8 * 16 + lr;
    int d = kq * 32 + lg * 8 + j;
    int h = e >> 4, f = e & 15;
    wl[i] = f2bf(saWk[(long long)l * 16384 + ((size_t)h * D_ + d) * F_ + f]);
  } else if (i < 425984) {                // sWv frag
    int il = i - 409600;
    int j = il & 7;
    int lane = (il >> 3) & 63;
    int nk = il >> 9;
    int kq = nk & 3, n8 = nk >> 2;
    int lr = lane & 15, lg = lane >> 4;
    int e = n8 * 16 + lr;
    int d = kq * 32 + lg * 8 + j;
    int h = e >> 4, f = e & 15;
    wl[i] = f2bf(saWv[(long long)l * 16384 + ((size_t)h * D_ + d) * F_ + f]);
  } else if (i < 429056) {                // bqP[n][e]
    int j = i - 425984;
    int n = j >> 7, e = j & 127, h = e >> 4, f = e & 15;
    fl[j] = sabq[l * 3072 + ((size_t)h * N_ + n) * F_ + f];
  } else if (i < 429184) {
    int j = i - 429056, h = j >> 4, f = j & 15;
    fl[3072 + j] = sabk[l * 128 + h * F_ + f];
  } else if (i < 429312) {
    int j = i - 429184, h = j >> 4, f = j & 15;
    fl[3200 + j] = sabv[l * 128 + h * F_ + f];
  }
}

// ---------------- transposed weight packing -> FRAGMENT layout -------------------
struct PackWArgs {
  const float* src[6];     // layer-0 bases: taWq, taWk, taWv, taWo, ffW1, ffW2
  ushort* wts;
};
__global__ __launch_bounds__(256) void k_pack_w(PackWArgs args)
{
  __shared__ float tile[64][65];
  int l = blockIdx.y;
  int x = blockIdx.x;
  ushort* wl = args.wts + (long long)l * WL_;
  const float* sp; ushort* dp;
  int bx, by, Rr, Cc, mode;
  if (x < 384) {
    int ten = x / 96, rem = x % 96, g = rem / 4, tl = rem % 4;
    bx = tl & 1; by = tl >> 1; Rr = 128; Cc = 128; mode = 0;
    sp = args.src[ten] + (long long)l * 393216 + (long long)g * 16384;
    dp = wl + 425984 + (long long)ten * 393216 + (long long)g * 16384;
  } else if (x < 392) {
    int idx = x - 384; bx = idx & 3; by = idx >> 2; Rr = 128; Cc = 256; mode = 1;
    sp = args.src[4] + (long long)l * 32768;
    dp = wl + 1998848;
  } else {
    int idx = x - 392; bx = idx & 1; by = idx >> 1; Rr = 256; Cc = 128; mode = 2;
    sp = args.src[5] + (long long)l * 32768;
    dp = wl + 2031616;
  }
  int c0 = bx * 64, r0 = by * 64;
  int ci = threadIdx.x & 63, rq = threadIdx.x >> 6;
  #pragma unroll
  for (int k = 0; k < 16; ++k) {
    int r = rq * 16 + k;
    tile[r][ci] = sp[(long long)(r0 + r) * Cc + c0 + ci];
  }
  __syncthreads();
  int ri = threadIdx.x & 63, cq = threadIdx.x >> 6;
  #pragma unroll
  for (int k = 0; k < 16; ++k) {
    int c = cq * 16 + k;
    int eg = c0 + c;          // output-col (e) dim
    int kg = r0 + ri;         // k dim
    int idx;
    if (mode == 1)      idx = (eg >> 7) * 16384 + fragIdx(eg & 127, kg, 4);
    else if (mode == 2) idx = fragIdx(eg, kg, 8);
    else                idx = fragIdx(eg, kg, 4);
    dp[idx] = f2bf(tile[ri][c]);
  }
}

// ---------------- unified 6-projection MFMA GEMM (2 row-tiles/block) ------------
struct Qkv6Args {
  const ushort* W[6];
  const float* bias[6];
  ushort* C[6];
  long long wGroup[6];
  int biasGroup[6];
  int tpose[6];
};
__global__ __launch_bounds__(256) void k_qkv6(const ushort* __restrict__ A, Qkv6Args args)
{
  __shared__ ushort Wl[16384];          // 32 KB, flat fragment layout
  int p = blockIdx.y;
  int gz = blockIdx.z;
  int tid = threadIdx.x;
  int lane = tid & 63, wid = tid >> 6;
  int lr = lane & 15, lg = lane >> 4;
  {
    const ushort* Wf = args.W[p] + (long long)gz * args.wGroup[p];
    #pragma unroll
    for (int it = 0; it < 8; ++it) {
      int idx = (it * 256 + tid) << 3;
      *(uint4*)&Wl[idx] = *(const uint4*)(Wf + idx);
    }
  }
  __syncthreads();
  const float* bb = args.bias[p] + (long long)gz * args.biasGroup[p];
  #pragma unroll
  for (int tt = 0; tt < 2; ++tt) {
    int row0 = (blockIdx.x * 2 + tt) * 64 + wid * 16;
    bf16x8_t au[4];
    {
      const ushort* ap = A + (long long)gz * 128 + (long long)(row0 + lr) * ND_ + lg * 8;
      #pragma unroll
      for (int kq = 0; kq < 4; ++kq)
        au[kq] = *(const bf16x8_t*)(ap + kq * 32);
    }
    f32x4_t acc[8];
    #pragma unroll
    for (int n = 0; n < 8; ++n) acc[n] = (f32x4_t){0.f, 0.f, 0.f, 0.f};
    #pragma unroll
    for (int n = 0; n < 8; ++n) {
      #pragma unroll
      for (int kq = 0; kq < 4; ++kq) {
        bf16x8_t bu = *(const bf16x8_t*)&Wl[((n * 4 + kq) * 64 + lane) << 3];
        acc[n] = __builtin_amdgcn_mfma_f32_16x16x32_bf16(au[kq], bu, acc[n], 0, 0, 0);
      }
    }
    if (args.tpose[p]) {
      ushort* Cp = args.C[p];
      #pragma unroll
      for (int n = 0; n < 8; ++n) {
        float bv = bb[n * 16 + lr];
        #pragma unroll
        for (int r = 0; r < 4; ++r) {
          int rg = row0 + lg * 4 + r;
          int ttg = rg >> 4, bI = rg & 15;
          long long gI = ((long long)bI * N_ + gz) * H_ + n;
          Cp[(gI * T_ + ttg) * F_ + lr] = f2bf(acc[n][r] + bv);
        }
      }
    } else {
      ushort* Cp = args.C[p] + (long long)gz * 128;
      #pragma unroll
      for (int n = 0; n < 8; ++n) {
        float bv = bb[n * 16 + lr];
        #pragma unroll
        for (int r = 0; r < 4; ++r)
          Cp[(long long)(row0 + lg * 4 + r) * ND_ + n * 16 + lr] = f2bf(acc[n][r] + bv);
      }
    }
  }
}

// ---------------- FF1 (flat-LDS frag staging), relu -> bf16 out ----------------
__global__ __launch_bounds__(256) void k_ff1(
    const ushort* __restrict__ A, const ushort* __restrict__ Wt,
    const float* __restrict__ bias, ushort* __restrict__ Cout)
{
  __shared__ ushort Wl[16384];
  int tid = threadIdx.x;
  int lane = tid & 63, wid = tid >> 6;
  int lr = lane & 15, lg = lane >> 4;
  int row0 = blockIdx.x * 64 + wid * 16;
  {
    const ushort* Wf = Wt + (long long)blockIdx.y * 16384;
    #pragma unroll
    for (int it = 0; it < 8; ++it) {
      int idx = (it * 256 + tid) << 3;
      *(uint4*)&Wl[idx] = *(const uint4*)(Wf + idx);
    }
  }
  bf16x8_t au[4];
  {
    const ushort* ap = A + (long long)(row0 + lr) * 128 + lg * 8;
    #pragma unroll
    for (int kq = 0; kq < 4; ++kq)
      au[kq] = *(const bf16x8_t*)(ap + kq * 32);
  }
  __syncthreads();
  f32x4_t acc[8];
  #pragma unroll
  for (int n = 0; n < 8; ++n) acc[n] = (f32x4_t){0.f, 0.f, 0.f, 0.f};
  #pragma unroll
  for (int n = 0; n < 8; ++n) {
    #pragma unroll
    for (int kq = 0; kq < 4; ++kq) {
      bf16x8_t bu = *(const bf16x8_t*)&Wl[((n * 4 + kq) * 64 + lane) << 3];
      acc[n] = __builtin_amdgcn_mfma_f32_16x16x32_bf16(au[kq], bu, acc[n], 0, 0, 0);
    }
  }
  const float* bb = bias + blockIdx.y * 128;
  int ccolBase = blockIdx.y * 128 + lr;
  #pragma unroll
  for (int n = 0; n < 8; ++n) {
    float bv = bb[n * 16 + lr];
    #pragma unroll
    for (int r = 0; r < 4; ++r) {
      float v = fmaxf(acc[n][r] + bv, 0.f);
      Cout[(long long)(row0 + lg * 4 + r) * 256 + ccolBase + n * 16] = f2bf(v);
    }
  }
}

// ---------------- FF2 + residual + per-joint LN_128 fused -> Xb ----------------
__global__ __launch_bounds__(256) void k_ff2_ln(
    const ushort* __restrict__ A,      // hB: 73728 x 256
    const ushort* __restrict__ Wt,     // W2 frag layout (KQ=8)
    const float* __restrict__ bias,    // ff_b2 (128)
    const ushort* __restrict__ Res,    // Ab flat 73728 x 128
    const float* __restrict__ g,       // lns_g (128)
    const float* __restrict__ be,      // lns_b (128)
    ushort* __restrict__ Xb)           // flat 73728 x 128
{
  __shared__ ushort Wl[32768];          // 64 KB, flat fragment layout
  int tid = threadIdx.x;
  int lane = tid & 63, wid = tid >> 6;
  int lr = lane & 15, lg = lane >> 4;
  int row0 = blockIdx.x * 64 + wid * 16;
  {
    #pragma unroll
    for (int it = 0; it < 16; ++it) {
      int idx = (it * 256 + tid) << 3;
      *(uint4*)&Wl[idx] = *(const uint4*)(Wt + idx);
    }
  }
  bf16x8_t au[8];
  {
    const ushort* ap = A + (long long)(row0 + lr) * 256 + lg * 8;
    #pragma unroll
    for (int kq = 0; kq < 8; ++kq)
      au[kq] = *(const bf16x8_t*)(ap + kq * 32);
  }
  __syncthreads();
  f32x4_t acc[8];
  #pragma unroll
  for (int n = 0; n < 8; ++n) acc[n] = (f32x4_t){0.f, 0.f, 0.f, 0.f};
  #pragma unroll
  for (int n = 0; n < 8; ++n) {
    #pragma unroll
    for (int kq = 0; kq < 8; ++kq) {
      bf16x8_t bu = *(const bf16x8_t*)&Wl[((n * 8 + kq) * 64 + lane) << 3];
      acc[n] = __builtin_amdgcn_mfma_f32_16x16x32_bf16(au[kq], bu, acc[n], 0, 0, 0);
    }
  }
  // epilogue: + bias + residual, per-row LN over 128
  float s[4] = {0.f, 0.f, 0.f, 0.f};
  float s2[4] = {0.f, 0.f, 0.f, 0.f};
  #pragma unroll
  for (int n = 0; n < 8; ++n) {
    float bv = bias[n * 16 + lr];
    #pragma unroll
    for (int r = 0; r < 4; ++r) {
      float v = acc[n][r] + bv
              + bf2f(Res[(long long)(row0 + lg * 4 + r) * 128 + n * 16 + lr]);
      acc[n][r] = v;
      s[r] += v;
      s2[r] += v * v;
    }
  }
  #pragma unroll
  for (int m = 1; m < 16; m <<= 1) {
    #pragma unroll
    for (int r = 0; r < 4; ++r) {
      s[r] += __shfl_xor(s[r], m, 64);
      s2[r] += __shfl_xor(s2[r], m, 64);
    }
  }
  #pragma unroll
  for (int r = 0; r < 4; ++r) {
    float mu = s[r] * (1.f / 128.f);
    float var = s2[r] * (1.f / 128.f) - mu * mu;
    float rs = rsqrtf(var + 1e-5f);
    long long rb = (long long)(row0 + lg * 4 + r) * 128;
    #pragma unroll
    for (int n = 0; n < 8; ++n) {
      int col = n * 16 + lr;
      Xb[rb + col] = f2bf((acc[n][r] - mu) * rs * g[col] + be[col]);
    }
  }
}

// ---------------- oproj (flat-LDS frag staging); A transposed TT layout ----------
__global__ __launch_bounds__(256) void k_oproj(const ushort* __restrict__ A,
                                               const ushort* __restrict__ Wt,
                                               const float* __restrict__ bias,
                                               ushort* __restrict__ Cout)
{
  __shared__ ushort Wl[16384];
  int gz = blockIdx.z;
  int tid = threadIdx.x;
  int lane = tid & 63, wid = tid >> 6;
  int lr = lane & 15, lg = lane >> 4;
  int row0 = blockIdx.x * 64 + wid * 16;   // multiple of 16 -> t uniform, b = lr
  int tW = row0 >> 4;
  {
    const ushort* Wf = Wt + (long long)gz * 16384;
    #pragma unroll
    for (int it = 0; it < 8; ++it) {
      int idx = (it * 256 + tid) << 3;
      *(uint4*)&Wl[idx] = *(const uint4*)(Wf + idx);
    }
  }
  union { bf16x8_t v; bf16x4_t h[2]; } au[4];
  {
    // sigma layout: slot(lg, hi*4+j) holds k = kq*32 + lg*8 + hi*4 + j
    // k -> h = 2*kq + (lg>>1), f = (lg&1)*8 + hi*4 + j
    const ushort* ab = A + (((long long)lr * N_ + gz) * H_ + (lg >> 1)) * ((long long)T_ * F_)
                         + (long long)tW * F_ + (lg & 1) * 8;
    #pragma unroll
    for (int kq = 0; kq < 4; ++kq) {
      au[kq].h[0] = *(const bf16x4_t*)(ab + (long long)(2 * kq) * (T_ * F_));
      au[kq].h[1] = *(const bf16x4_t*)(ab + (long long)(2 * kq) * (T_ * F_) + 4);
    }
  }
  __syncthreads();
  f32x4_t acc[8];
  #pragma unroll
  for (int n = 0; n < 8; ++n) acc[n] = (f32x4_t){0.f, 0.f, 0.f, 0.f};
  #pragma unroll
  for (int n = 0; n < 8; ++n) {
    #pragma unroll
    for (int kq = 0; kq < 4; ++kq) {
      bf16x8_t bu = *(const bf16x8_t*)&Wl[((n * 4 + kq) * 64 + lane) << 3];
      acc[n] = __builtin_amdgcn_mfma_f32_16x16x32_bf16(au[kq].v, bu, acc[n], 0, 0, 0);
    }
  }
  const float* bb = bias + (long long)gz * 128;
  ushort* C = Cout + (long long)gz * 128;
  #pragma unroll
  for (int n = 0; n < 8; ++n) {
    float bv = bb[n * 16 + lr];
    #pragma unroll
    for (int r = 0; r < 4; ++r)
      C[(long long)(row0 + lg * 4 + r) * ND_ + n * 16 + lr] = f2bf(acc[n][r] + bv);
  }
}

// ---------------- fused spatial attention + LN -> T2b, register-resident O --------
__global__ __launch_bounds__(256) void k_spatial_ln(const ushort* __restrict__ Qg,
                                                    const ushort* __restrict__ Kg,
                                                    const ushort* __restrict__ Vg,
                                                    const ushort* __restrict__ Xb,
                                                    const float* __restrict__ g,
                                                    const float* __restrict__ be,
                                                    ushort* __restrict__ T2b)
{
  int row = blockIdx.x;
  int tid = threadIdx.x;
  __shared__ float Ks[8 * 409];
  __shared__ float Vs[8 * 409];
  __shared__ float ps[4], ps2[4];
  {
    const uint4* K4 = (const uint4*)(Kg + (size_t)row * ND_);
    const uint4* V4 = (const uint4*)(Vg + (size_t)row * ND_);
    for (int i8 = tid; i8 < 384; i8 += 256) {
      int n = i8 >> 4, e8 = (i8 & 15) * 8;
      int h = e8 >> 4, f0 = e8 & 15;
      int basei = h * 409 + n * 17 + f0;
      union { uint4 u; ushort s[8]; } kv, vv;
      kv.u = K4[i8];
      vv.u = V4[i8];
      #pragma unroll
      for (int j = 0; j < 8; ++j) {
        Ks[basei + j] = bf2f(kv.s[j]);
        Vs[basei + j] = bf2f(vv.s[j]);
      }
    }
  }
  __syncthreads();
  float o[F_];
  float s = 0.f, s2 = 0.f;
  int n = tid >> 3, h = tid & 7;
  int cbase = n * D_ + h * F_;
  if (tid < 192) {
    float q[F_];
    {
      const ushort* qp = Qg + (size_t)row * ND_ + cbase;
      union { uint4 u[2]; ushort s[16]; } qv;
      qv.u[0] = *(const uint4*)qp;
      qv.u[1] = *(const uint4*)(qp + 8);
      #pragma unroll
      for (int f = 0; f < F_; ++f) q[f] = bf2f(qv.s[f]);
    }
    float sc[N_];
    float mx = -1e30f;
    const float* Kh = &Ks[h * 409];
    for (int m = 0; m < N_; ++m) {
      float sd = 0.f;
      #pragma unroll
      for (int f = 0; f < F_; ++f) sd += q[f] * Kh[m * 17 + f];
      sd *= 0.25f;
      sc[m] = sd;
      mx = fmaxf(mx, sd);
    }
    float den = 0.f;
    for (int m = 0; m < N_; ++m) { sc[m] = __expf(sc[m] - mx); den += sc[m]; }
    float inv = 1.f / den;
    #pragma unroll
    for (int f = 0; f < F_; ++f) o[f] = 0.f;
    const float* Vh = &Vs[h * 409];
    for (int m = 0; m < N_; ++m) {
      float p = sc[m] * inv;
      #pragma unroll
      for (int f = 0; f < F_; ++f) o[f] += p * Vh[m * 17 + f];
    }
    {
      const ushort* xp = Xb + (size_t)row * ND_ + cbase;
      union { uint4 u[2]; ushort s[16]; } xu;
      xu.u[0] = *(const uint4*)xp;
      xu.u[1] = *(const uint4*)(xp + 8);
      #pragma unroll
      for (int f = 0; f < F_; ++f) {
        float v = o[f] + bf2f(xu.s[f]);
        o[f] = v;
        s += v;
        s2 += v * v;
      }
    }
  }
  #pragma unroll
  for (int m = 1; m < 64; m <<= 1) {
    s += __shfl_xor(s, m, 64);
    s2 += __shfl_xor(s2, m, 64);
  }
  int w = tid >> 6;
  if ((tid & 63) == 0) { ps[w] = s; ps2[w] = s2; }
  __syncthreads();
  float ts = ps[0] + ps[1] + ps[2] + ps[3];
  float ts2 = ps2[0] + ps2[1] + ps2[2] + ps2[3];
  float mu = ts / (float)ND_;
  float var = ts2 / (float)ND_ - mu * mu;
  float rs = rsqrtf(var + 1e-5f);
  if (tid < 192) {
    union { uint4 u[2]; ushort s[16]; } ov;
    #pragma unroll
    for (int f = 0; f < F_; ++f)
      ov.s[f] = f2bf((o[f] - mu) * rs * g[cbase + f] + be[cbase + f]);
    ushort* op = T2b + (size_t)row * ND_ + cbase;
    *(uint4*)op = ov.u[0];
    *(uint4*)(op + 8) = ov.u[1];
  }
}

// ---------------- temporal attention via MFMA, fused per-K-pair pipeline ----------
__global__ __launch_bounds__(256) void k_temporal_mfma(const ushort* __restrict__ tQ,
                                                       const ushort* __restrict__ tK,
                                                       const ushort* __restrict__ tV,
                                                       ushort* __restrict__ Ob)
{
  long long gb = (long long)blockIdx.x * (T_ * F_);
  int tid = threadIdx.x;
  __shared__ ushort Kl[T_][20];
  __shared__ ushort Ql[T_][20];
  __shared__ ushort Vt[F_][200];
  {
    const uint4* Kg4 = (const uint4*)(tK + gb);
    const uint4* Qg4 = (const uint4*)(tQ + gb);
    const uint4* Vg4 = (const uint4*)(tV + gb);
    for (int task = tid; task < 1152; task += 256) {
      int ten = task / 384, idx = task - ten * 384;
      int t = idx >> 1, half = idx & 1;
      if (ten == 0) {
        uint4 v = Kg4[idx];
        *(uint2*)&Kl[t][half * 8] = make_uint2(v.x, v.y);
        *(uint2*)&Kl[t][half * 8 + 4] = make_uint2(v.z, v.w);
      } else if (ten == 1) {
        uint4 v = Qg4[idx];
        *(uint2*)&Ql[t][half * 8] = make_uint2(v.x, v.y);
        *(uint2*)&Ql[t][half * 8 + 4] = make_uint2(v.z, v.w);
      } else {
        union { uint4 u4; ushort s[8]; } vv;
        vv.u4 = Vg4[idx];
        #pragma unroll
        for (int f = 0; f < 8; ++f) Vt[half * 8 + f][t] = vv.s[f];
      }
    }
  }
  __syncthreads();
  int lane = tid & 63, wid = tid >> 6;
  int lr = lane & 15, lg = lane >> 4;
  const bf16x4_t z4 = (bf16x4_t){0, 0, 0, 0};
  const f32x4_t zf = (f32x4_t){0.f, 0.f, 0.f, 0.f};
  #pragma unroll
  for (int jj = 0; jj < 3; ++jj) {
    int q0 = (wid * 3 + jj) * 16;
    union { bf16x8_t v; bf16x4_t h4[2]; } qf;
    qf.h4[0] = *(const bf16x4_t*)&Ql[q0 + lr][lg * 4];
    qf.h4[1] = z4;
    int qg = q0 + lr;
    float lsum = 0.f;
    f32x4_t o = zf;
    #pragma unroll
    for (int i = 0; i < 6; ++i) {
      union { bf16x8_t v; bf16x4_t h4[2]; } kf0, kf1;
      kf0.h4[0] = *(const bf16x4_t*)&Kl[(2 * i) * 16 + lr][lg * 4];
      kf0.h4[1] = z4;
      kf1.h4[0] = *(const bf16x4_t*)&Kl[(2 * i + 1) * 16 + lr][lg * 4];
      kf1.h4[1] = z4;
      f32x4_t d0 = __builtin_amdgcn_mfma_f32_16x16x32_bf16(kf0.v, qf.v, zf, 0, 0, 0);
      f32x4_t d1 = __builtin_amdgcn_mfma_f32_16x16x32_bf16(kf1.v, qf.v, zf, 0, 0, 0);
      #pragma unroll
      for (int r = 0; r < 4; ++r) {
        int k = (2 * i) * 16 + lg * 4 + r;
        float p = __expf(d0[r] * 0.25f + ((k < qg) ? 1.0f : 0.0f));
        d0[r] = p;
        lsum += p;
      }
      #pragma unroll
      for (int r = 0; r < 4; ++r) {
        int k = (2 * i + 1) * 16 + lg * 4 + r;
        float p = __expf(d1[r] * 0.25f + ((k < qg) ? 1.0f : 0.0f));
        d1[r] = p;
        lsum += p;
      }
      union { bf16x8_t v; bf16x4_t h4[2]; } vf;
      vf.h4[0] = *(const bf16x4_t*)&Vt[lr][i * 32 + lg * 4];
      vf.h4[1] = *(const bf16x4_t*)&Vt[lr][i * 32 + 16 + lg * 4];
      union { bf16x8_t v; uint uu[4]; } pf;
      pf.uu[0] = cvtpk(d0[0], d0[1]);
      pf.uu[1] = cvtpk(d0[2], d0[3]);
      pf.uu[2] = cvtpk(d1[0], d1[1]);
      pf.uu[3] = cvtpk(d1[2], d1[3]);
      o = __builtin_amdgcn_mfma_f32_16x16x32_bf16(vf.v, pf.v, o, 0, 0, 0);
    }
    lsum += __shfl_xor(lsum, 16, 64);
    lsum += __shfl_xor(lsum, 32, 64);
    float inv = 1.f / lsum;
    bf16x4_t ov;
    #pragma unroll
    for (int r = 0; r < 4; ++r) ov[r] = (short)f2bf(o[r] * inv);
    *(bf16x4_t*)(Ob + gb + (long long)qg * F_ + lg * 4) = ov;
  }
}

// ---------------- Ab = T2b + LN(Opjb + Xb)  (register-resident, no LDS buf) -------
__global__ __launch_bounds__(256) void k_lnres_add(const ushort* __restrict__ Ain,
                                                   const ushort* __restrict__ Xb,
                                                   const ushort* __restrict__ T2,
                                                   const float* __restrict__ g,
                                                   const float* __restrict__ be,
                                                   ushort* __restrict__ Ab)
{
  int row = blockIdx.x;
  int tid = threadIdx.x;
  __shared__ float ps[4], ps2[4];
  const uint4* Ar = (const uint4*)(Ain + (size_t)row * ND_);
  const uint4* Xr = (const uint4*)(Xb + (size_t)row * ND_);
  float v0[8], v1[8];
  float s = 0.f, s2 = 0.f;
  {
    uint4 av = Ar[tid], xv = Xr[tid];
    const ushort* ap = (const ushort*)&av;
    const ushort* xp = (const ushort*)&xv;
    #pragma unroll
    for (int j = 0; j < 8; ++j) {
      float v = bf2f(ap[j]) + bf2f(xp[j]);
      v0[j] = v;
      s += v;
      s2 += v * v;
    }
  }
  if (tid < 128) {
    uint4 av = Ar[tid + 256], xv = Xr[tid + 256];
    const ushort* ap = (const ushort*)&av;
    const ushort* xp = (const ushort*)&xv;
    #pragma unroll
    for (int j = 0; j < 8; ++j) {
      float v = bf2f(ap[j]) + bf2f(xp[j]);
      v1[j] = v;
      s += v;
      s2 += v * v;
    }
  }
  #pragma unroll
  for (int m = 1; m < 64; m <<= 1) {
    s += __shfl_xor(s, m, 64);
    s2 += __shfl_xor(s2, m, 64);
  }
  int w = tid >> 6;
  if ((tid & 63) == 0) { ps[w] = s; ps2[w] = s2; }
  __syncthreads();
  float ts = ps[0] + ps[1] + ps[2] + ps[3];
  float ts2 = ps2[0] + ps2[1] + ps2[2] + ps2[3];
  float mu = ts / (float)ND_;
  float var = ts2 / (float)ND_ - mu * mu;
  float rs = rsqrtf(var + 1e-5f);
  const uint4* Tr = (const uint4*)(T2 + (size_t)row * ND_);
  uint4* Or = (uint4*)(Ab + (size_t)row * ND_);
  {
    uint4 tv = Tr[tid];
    const ushort* tp = (const ushort*)&tv;
    uint4 ov;
    ushort* op = (ushort*)&ov;
    int i0 = tid * 8;
    #pragma unroll
    for (int j = 0; j < 8; ++j)
      op[j] = f2bf((v0[j] - mu) * rs * g[i0 + j] + be[i0 + j] + bf2f(tp[j]));
    Or[tid] = ov;
  }
  if (tid < 128) {
    uint4 tv = Tr[tid + 256];
    const ushort* tp = (const ushort*)&tv;
    uint4 ov;
    ushort* op = (ushort*)&ov;
    int i0 = (tid + 256) * 8;
    #pragma unroll
    for (int j = 0; j < 8; ++j)
      op[j] = f2bf((v1[j] - mu) * rs * g[i0 + j] + be[i0 + j] + bf2f(tp[j]));
    Or[tid + 256] = ov;
  }
}

// ---------------- final projection + input residual (padded LDS, no conflicts) ---
__global__ __launch_bounds__(256) void k_final(const ushort* __restrict__ Xb,
                                               const float* __restrict__ Wf,
                                               const float* __restrict__ bf,
                                               const float* __restrict__ in,
                                               float* __restrict__ out)
{
  int row = blockIdx.x;   // t*B + b
  int t = row / B_, b = row % B_;
  int tid = threadIdx.x;
  __shared__ float xr[N_][132];   // stride 132: bank = (4n+d)%32, distinct per n
  const uint4* Xr = (const uint4*)(Xb + (size_t)row * ND_);
  for (int i8 = tid; i8 < ND_ / 8; i8 += 256) {
    uint4 xv = Xr[i8];
    const ushort* xp = (const ushort*)&xv;
    int n = i8 >> 4, d0 = (i8 & 15) * 8;
    #pragma unroll
    for (int j = 0; j < 8; ++j) xr[n][d0 + j] = bf2f(xp[j]);
  }
  __syncthreads();
  if (tid < N_ * M_) {
    int n = tid / M_, mm = tid % M_;
    const float* xn = xr[n];
    float a0 = bf[mm], a1 = 0.f, a2 = 0.f, a3 = 0.f;
    for (int d = 0; d < D_; d += 4) {
      a0 += xn[d]     * Wf[(size_t)d * M_ + mm];
      a1 += xn[d + 1] * Wf[(size_t)(d + 1) * M_ + mm];
      a2 += xn[d + 2] * Wf[(size_t)(d + 2) * M_ + mm];
      a3 += xn[d + 3] * Wf[(size_t)(d + 3) * M_ + mm];
    }
    size_t oi = ((size_t)b * T_ + t) * (N_ * M_) + tid;
    out[oi] = ((a0 + a1) + (a2 + a3)) + in[oi];
  }
}

extern "C" void kernel_launch(void* const* d_in, const int* in_sizes, int n_in,
                              void* d_out, int out_size, void* d_ws, size_t ws_size,
                              hipStream_t stream)
{
  const float* inputs = (const float*)d_in[0];
  const float* emb_W  = (const float*)d_in[1];
  const float* emb_b  = (const float*)d_in[2];
  const float* sa_Wq  = (const float*)d_in[3];
  const float* sa_bq  = (const float*)d_in[4];
  const float* sa_Wk  = (const float*)d_in[5];
  const float* sa_bk  = (const float*)d_in[6];
  const float* sa_Wv  = (const float*)d_in[7];
  const float* sa_bv  = (const float*)d_in[8];
  const float* ta_Wq  = (const float*)d_in[9];
  const float* ta_bq  = (const float*)d_in[10];
  const float* ta_Wk  = (const float*)d_in[11];
  const float* ta_bk  = (const float*)d_in[12];
  const float* ta_Wv  = (const float*)d_in[13];
  const float* ta_bv  = (const float*)d_in[14];
  const float* ta_Wo  = (const float*)d_in[15];
  const float* ta_bo  = (const float*)d_in[16];
  const float* ln_g   = (const float*)d_in[17];
  const float* ln_b   = (const float*)d_in[18];
  const float* lns_g  = (const float*)d_in[19];
  const float* lns_b  = (const float*)d_in[20];
  const float* ff_W1  = (const float*)d_in[21];
  const float* ff_b1  = (const float*)d_in[22];
  const float* ff_W2  = (const float*)d_in[23];
  const float* ff_b2  = (const float*)d_in[24];
  const float* fin_W  = (const float*)d_in[25];
  const float* fin_b  = (const float*)d_in[26];
  float* out = (float*)d_out;

  // ---- workspace layout ----
  char* base = (char*)d_ws;
  ushort* Xb  = (ushort*)base;                       // [0, 2SZ)
  ushort* C0  = (ushort*)(base + 2 * SZ_);           // [2SZ, 14SZ): slots S0..S5
  ushort* T2b = (ushort*)(base + 14 * SZ_);          // [14SZ, 16SZ)
  ushort* sQ = C0;                       // S0
  ushort* sK = C0 + SZ_;                 // S1
  ushort* sV = C0 + 2 * SZ_;             // S2
  ushort* tQ = C0 + 3 * SZ_;             // S3 (transposed layout)
  ushort* tK = C0 + 4 * SZ_;             // S4 (transposed layout)
  ushort* tV = C0 + 5 * SZ_;             // S5 (transposed layout)
  ushort* AOb  = tV;                     // temporal attn writes S5 in place
  ushort* Opjb = sQ;                     // oproj out -> S0
  ushort* Ab   = sK;                     // lnres_add out -> S1
  ushort* hB   = tK;                     // FF hidden -> S4+S5

  ushort* wts = (ushort*)(base + 16 * SZ_);          // 2 layers x WL_
  float* fb   = (float*)(wts + 2 * WL_);             // 2 layers x 3328
  float* peT  = fb + 2 * 3328;                       // 589824

  // ---- both layers' weight packing (fragment layout), hoisted ----
  k_pack_sp<<<dim3(1677, 2), 256, 0, stream>>>(sa_Wq, sa_bq, sa_Wk, sa_bk,
                                               sa_Wv, sa_bv, wts, fb);
  PackWArgs pw;
  pw.src[0] = ta_Wq; pw.src[1] = ta_Wk; pw.src[2] = ta_Wv; pw.src[3] = ta_Wo;
  pw.src[4] = ff_W1; pw.src[5] = ff_W2;
  pw.wts = wts;
  k_pack_w<<<dim3(400, 2), 256, 0, stream>>>(pw);

  k_pe<<<(T_ * ND_ + 255) / 256, 256, 0, stream>>>(peT);
  k_embed<<<ROWS_, 256, 0, stream>>>(inputs, emb_W, emb_b, peT, Xb);

  for (int l = 0; l < 2; ++l) {
    ushort* wl = wts + (long long)l * WL_;
    ushort* sWq = wl;
    ushort* sWk = wl + 393216;
    ushort* sWv = wl + 409600;
    ushort* tWq = wl + 425984;
    ushort* tWk = wl + 819200;
    ushort* tWv = wl + 1212416;
    ushort* tWo = wl + 1605632;
    ushort* W1t = wl + 1998848;
    ushort* W2t = wl + 2031616;
    float* fl = fb + l * 3328;
    float* bqP = fl;
    float* bkP = fl + 3072;
    float* bvP = fl + 3200;

    Qkv6Args qa;
    qa.W[0] = sWk; qa.bias[0] = bkP;                         qa.C[0] = sK;
    qa.wGroup[0] = 0;     qa.biasGroup[0] = 0;   qa.tpose[0] = 0;
    qa.W[1] = sWv; qa.bias[1] = bvP;                         qa.C[1] = sV;
    qa.wGroup[1] = 0;     qa.biasGroup[1] = 0;   qa.tpose[1] = 0;
    qa.W[2] = sWq; qa.bias[2] = bqP;                         qa.C[2] = sQ;
    qa.wGroup[2] = 16384; qa.biasGroup[2] = 128; qa.tpose[2] = 0;
    qa.W[3] = tWq; qa.bias[3] = ta_bq + (size_t)l * N_ * D_; qa.C[3] = tQ;
    qa.wGroup[3] = 16384; qa.biasGroup[3] = 128; qa.tpose[3] = 1;
    qa.W[4] = tWk; qa.bias[4] = ta_bk + (size_t)l * N_ * D_; qa.C[4] = tK;
    qa.wGroup[4] = 16384; qa.biasGroup[4] = 128; qa.tpose[4] = 1;
    qa.W[5] = tWv; qa.bias[5] = ta_bv + (size_t)l * N_ * D_; qa.C[5] = tV;
    qa.wGroup[5] = 16384; qa.biasGroup[5] = 128; qa.tpose[5] = 1;
    k_qkv6<<<dim3(ROWS_ / 128, 6, N_), 256, 0, stream>>>(Xb, qa);

    k_spatial_ln<<<ROWS_, 256, 0, stream>>>(sQ, sK, sV, Xb, ln_g + (size_t)l * ND_,
                                            ln_b + (size_t)l * ND_, T2b);

    k_temporal_mfma<<<B_ * N_ * H_, 256, 0, stream>>>(tQ, tK, tV, AOb);
    k_oproj<<<dim3(ROWS_ / 64, 1, N_), 256, 0, stream>>>(
        AOb, tWo, ta_bo + (size_t)l * N_ * D_, Opjb);

    k_lnres_add<<<ROWS_, 256, 0, stream>>>(Opjb, Xb, T2b, ln_g + (size_t)l * ND_,
                                           ln_b + (size_t)l * ND_, Ab);

    k_ff1<<<dim3(ROWS_ * N_ / 64, 2, 1), 256, 0, stream>>>(
        Ab, W1t, ff_b1 + (size_t)l * FF_, hB);
    k_ff2_ln<<<dim3(ROWS_ * N_ / 64, 1, 1), 256, 0, stream>>>(
        hB, W2t, ff_b2 + (size_t)l * D_, Ab,
        lns_g + (size_t)l * D_, lns_b + (size_t)l * D_, Xb);
  }

  k_final<<<ROWS_, 256, 0, stream>>>(Xb, fin_W, fin_b, inputs, out);
}